// Round 15
// baseline (480.841 us; speedup 1.0000x reference)
//
#include <hip/hip_runtime.h>

#define NN 50000
#define EE 100000
#define FF 64
#define HH 128
#define HEADS 4
#define BB 64
#define SS 512
#define LCC 8

// ---- bf16 helpers ----
__device__ __forceinline__ float b2f(ushort u) {
    return __uint_as_float(((unsigned)u) << 16);
}
__device__ __forceinline__ ushort f2b(float f) {
    unsigned u = __float_as_uint(f);
    unsigned r = (u + 0x7FFFu + ((u >> 16) & 1u)) >> 16;   // RNE
    return (ushort)r;
}

typedef __attribute__((ext_vector_type(4))) float f32x4;
typedef __attribute__((ext_vector_type(8))) short s16x8;
typedef __attribute__((ext_vector_type(8))) ushort u16x8;

__device__ __forceinline__ void glls16(const ushort* g, ushort* l) {
    __builtin_amdgcn_global_load_lds((const __attribute__((address_space(1))) void*)g,
                                     (__attribute__((address_space(3))) void*)l, 16, 0, 0);
}

// ================= bf16 MFMA GEMM (r12-proven core) =================
#define BM 128
#define BN 128
#define BK 64
#define EST 68   // epilogue staging stride (f32) — breaks power-of-2 bank aliasing

__global__ __launch_bounds__(256) void gemm_bf16(
    const ushort* __restrict__ A, const ushort* __restrict__ Bt,
    const float* __restrict__ bias,
    ushort* __restrict__ C1, int ld1,
    ushort* __restrict__ C2b, int mode,
    int M, int K, int relu, int gx, int gy)
{
    __shared__ __align__(16) ushort Sm[2 * BM * BK];   // 32 KB: As | Bs, reused by epilogue
    ushort* As = Sm;
    ushort* Bs = Sm + BM * BK;

    const int bid  = blockIdx.x;
    const int xcd  = bid & 7;
    const int slot = bid >> 3;
    const int bx   = slot % gx;
    const int by   = xcd + 8 * (slot / gx);
    if (by >= gy) return;
    const int m0 = by * BM;
    const int n0 = bx * BN;

    const int t = threadIdx.x;
    const int lane = t & 63;
    const int wave = t >> 6;
    const int wm = (wave & 1) * 64;
    const int wn = (wave >> 1) * 64;
    const int lrow = lane & 15;
    const int g    = lane >> 4;

    const int srow = (wave << 5) + (lane >> 3);
    const int scs  = lane & 7;

    const ushort* ga[4];
    const ushort* gb[4];
#pragma unroll
    for (int p = 0; p < 4; ++p) {
        const int row = srow + (p << 3);
        const int l   = scs ^ (row & 7);
        ga[p] = A + (size_t)min(m0 + row, M - 1) * K + (l << 3);
        gb[p] = Bt + (size_t)(n0 + row) * K + (l << 3);
    }
    const int ldsoff = (wave << 11);

    f32x4 acc[4][4] = {};

    for (int k0 = 0; k0 < K; k0 += BK) {
#pragma unroll
        for (int p = 0; p < 4; ++p) glls16(ga[p] + k0, As + ldsoff + (p << 9));
#pragma unroll
        for (int p = 0; p < 4; ++p) glls16(gb[p] + k0, Bs + ldsoff + (p << 9));
        __syncthreads();

#pragma unroll
        for (int kk = 0; kk < 2; ++kk) {
            s16x8 af[4], bf[4];
#pragma unroll
            for (int i = 0; i < 4; ++i) {
                const int R = wm + i * 16 + lrow;
                const int c = ((kk << 2) + g) ^ (R & 7);
                af[i] = *(const s16x8*)&As[(R << 6) + (c << 3)];
            }
#pragma unroll
            for (int j = 0; j < 4; ++j) {
                const int R = wn + j * 16 + lrow;
                const int c = ((kk << 2) + g) ^ (R & 7);
                bf[j] = *(const s16x8*)&Bs[(R << 6) + (c << 3)];
            }
#pragma unroll
            for (int i = 0; i < 4; ++i)
#pragma unroll
                for (int j = 0; j < 4; ++j)
                    acc[i][j] = __builtin_amdgcn_mfma_f32_16x16x32_bf16(af[i], bf[j], acc[i][j], 0, 0, 0);
        }
        __syncthreads();
    }

    // ---- LDS-staged epilogue ----
    float* Es = (float*)Sm + wave * (16 * EST);

    const int wbase = n0 + wn;
    ushort* Cw; int ldw, cb;
    if (mode == 0) { Cw = C1; ldw = ld1; cb = wbase; }
    else if (mode == 1) {
        if (wbase < 512) { Cw = C1; ldw = ld1; cb = wbase; }
        else {
            const int u = wbase - 512;
            const int h = u >> 8;                // 256 cols per head: u(128) | v(128)
            cb = u & 255;
            Cw = C2b + (size_t)h * NN * 256; ldw = 256;
        }
    } else {
        if (wbase < 128) { Cw = C1; ldw = 128; cb = wbase; }
        else             { Cw = C2b; ldw = 384; cb = wbase - 128; }
    }

    float bj[4];
#pragma unroll
    for (int j = 0; j < 4; ++j) bj[j] = bias[wbase + j * 16 + lrow];

    const int rbase = (lane >> 4) * 4;
    const int rrow  = lane >> 2;
    const int rcol  = (lane & 3) << 4;

#pragma unroll
    for (int i = 0; i < 4; ++i) {
#pragma unroll
        for (int j = 0; j < 4; ++j)
#pragma unroll
            for (int r = 0; r < 4; ++r) {
                float v = acc[i][j][r] + bj[j];
                if (relu) v = fmaxf(v, 0.f);
                Es[(rbase + r) * EST + j * 16 + lrow] = v;
            }
        const int gm = m0 + wm + i * 16 + rrow;
        if (gm < M) {
            const float* src = Es + rrow * EST + rcol;
            f32x4 f0 = *(const f32x4*)(src + 0);
            f32x4 f1 = *(const f32x4*)(src + 4);
            f32x4 f2 = *(const f32x4*)(src + 8);
            f32x4 f3 = *(const f32x4*)(src + 12);
            u16x8 o0, o1;
            o0[0] = f2b(f0[0]); o0[1] = f2b(f0[1]); o0[2] = f2b(f0[2]); o0[3] = f2b(f0[3]);
            o0[4] = f2b(f1[0]); o0[5] = f2b(f1[1]); o0[6] = f2b(f1[2]); o0[7] = f2b(f1[3]);
            o1[0] = f2b(f2[0]); o1[1] = f2b(f2[1]); o1[2] = f2b(f2[2]); o1[3] = f2b(f2[3]);
            o1[4] = f2b(f3[0]); o1[5] = f2b(f3[1]); o1[6] = f2b(f3[2]); o1[7] = f2b(f3[3]);
            ushort* dst = Cw + (size_t)gm * ldw + cb + rcol;
            *(u16x8*)(dst + 0) = o0;
            *(u16x8*)(dst + 8) = o1;
        }
    }
}

// ================= weight prep =================
#define F1OFF  8192
#define F2OFF  204800
#define WTOTAL 466944
#define BTOT   2048

__global__ void wprep_kernel(
    const float* __restrict__ Wp,
    const float* __restrict__ Wq1, const float* __restrict__ Wk1,
    const float* __restrict__ Wv1, const float* __restrict__ Ws1,
    const float* __restrict__ Wq2, const float* __restrict__ Wk2,
    const float* __restrict__ Wv2, const float* __restrict__ Ws2,
    const float* __restrict__ bs1, const float* __restrict__ bv1,
    const float* __restrict__ bs2,
    const float* __restrict__ bq2, const float* __restrict__ bk2, const float* __restrict__ bv2,
    ushort* __restrict__ wt, float* __restrict__ bb)
{
    int t = blockIdx.x * 256 + threadIdx.x;
    if (t < WTOTAL) {
        float v;
        if (t < F1OFF) {
            int n = t >> 6, k = t & 63;
            v = Wp[k * 128 + n];
        } else if (t < F2OFF) {
            int u = t - F1OFF;
            int n = u >> 7, k = u & 127;
            if (n < 512) v = Ws1[k * 512 + n];
            else {
                int r = n - 512;
                int h = r >> 8, c = r & 255;
                if (c < 128) return;             // u (M) rows: filled by mcomp_kernel
                v = Wv1[k * 512 + h * 128 + (c - 128)];
            }
        } else {
            int u = t - F2OFF;
            int n = u >> 9, k = u & 511;
            if (n < 128) v = Ws2[k * 128 + n];
            else {
                int r = n - 128;
                const float* W = (r < 128) ? Wq2 : (r < 256) ? Wk2 : Wv2;
                v = W[k * 128 + (r & 127)];
            }
        }
        wt[t] = f2b(v);
    } else if (t < WTOTAL + BTOT) {
        int u = t - WTOTAL;
        float v;
        if (u < 512) v = bs1[u];
        else if (u < 1536) {
            int r = u - 512;
            int h = r >> 8, c = r & 255;
            if (c < 128) return;                 // r_h bias: filled by mcomp_kernel
            v = bv1[h * 128 + (c - 128)];
        } else {
            int c = u - 1536;
            v = (c < 128) ? bs2[c]
              : (c < 256) ? bq2[c - 128]
              : (c < 384) ? bk2[c - 256] : bv2[c - 384];
        }
        bb[u] = v;
    }
}

// ================= mcomp: per-head M = Wq Wk^T (bf16) and r = Wk bq (fp32 bias) ====
__global__ void mcomp_kernel(
    const float* __restrict__ Wq1, const float* __restrict__ Wk1,
    const float* __restrict__ bq1, ushort* __restrict__ wt, float* __restrict__ bb)
{
    int t = blockIdx.x * 256 + threadIdx.x;
    if (t < HEADS * 128 * 128) {
        int h = t >> 14;
        int rem = t & 16383;
        int b = rem >> 7, a = rem & 127;
        const float* wq = Wq1 + a * 512 + h * 128;
        const float* wk = Wk1 + b * 512 + h * 128;
        float acc = 0.f;
#pragma unroll 8
        for (int d = 0; d < 128; ++d) acc += wq[d] * wk[d];
        wt[F1OFF + (size_t)(512 + h * 256 + b) * 128 + a] = f2b(acc);
    } else if (t < HEADS * 128 * 128 + HEADS * 128) {
        int u = t - HEADS * 128 * 128;
        int h = u >> 7, b = u & 127;
        const float* wk = Wk1 + b * 512 + h * 128;
        const float* bq = bq1 + h * 128;
        float acc = 0.f;
#pragma unroll 8
        for (int d = 0; d < 128; ++d) acc += wk[d] * bq[d];
        bb[512 + h * 256 + b] = acc;
    }
}

// ================= fp32 -> bf16 (x4) =================
__global__ void f32_to_bf16_kernel(const float4* __restrict__ in, ushort4* __restrict__ out, int n4)
{
    int i = blockIdx.x * 256 + threadIdx.x;
    if (i >= n4) return;
    float4 v = in[i];
    ushort4 o;
    o.x = f2b(v.x); o.y = f2b(v.y); o.z = f2b(v.z); o.w = f2b(v.w);
    out[i] = o;
}

__global__ void fill_kernel(unsigned* __restrict__ p, unsigned v, int n) {
    int i = blockIdx.x * blockDim.x + threadIdx.x;
    if (i < n) p[i] = v;
}

// ================= CSR build (dst -> src list) =================
__global__ void hist_kernel(const int* __restrict__ dst, int* __restrict__ cnt, int E) {
    int e = blockIdx.x * 256 + threadIdx.x;
    if (e < E) atomicAdd(&cnt[dst[e]], 1);
}

// single-block exclusive scan: rowptr[0..n] and cursor[0..n) in ONE dispatch
#define SCT 1024
__global__ __launch_bounds__(SCT) void scan_kernel(
    const int* __restrict__ cnt, int* __restrict__ rowptr, int* __restrict__ cursor, int n)
{
    __shared__ int sd[SCT];
    const int tid = threadIdx.x;
    const int per = (n + SCT - 1) / SCT;     // 49
    const int base = tid * per;
    int s = 0;
    for (int j = 0; j < per; ++j) {
        int idx = base + j;
        if (idx < n) s += cnt[idx];
    }
    sd[tid] = s;
    __syncthreads();
    for (int off = 1; off < SCT; off <<= 1) {
        int t2 = (tid >= off) ? sd[tid - off] : 0;
        __syncthreads();
        sd[tid] += t2;
        __syncthreads();
    }
    int acc = sd[tid] - s;                   // exclusive prefix of this thread's chunk
    for (int j = 0; j < per; ++j) {
        int idx = base + j;
        if (idx < n) {
            cursor[idx] = acc;
            acc += cnt[idx];
            rowptr[idx + 1] = acc;
        }
    }
    if (tid == 0) rowptr[0] = 0;
}

__global__ void bucket_kernel(const int* __restrict__ src, const int* __restrict__ dst,
                              int* __restrict__ cursor, int* __restrict__ srcs, int E) {
    int e = blockIdx.x * 256 + threadIdx.x;
    if (e >= E) return;
    int p = atomicAdd(&cursor[dst[e]], 1);
    srcs[p] = src[e];
}

// ================= conv1 gather: ALL 4 HEADS per wave (one wave per node) =================
// Qb: 4 head buffers (stride NN*256 us), row = [u(128)|v(128)]. Kb = h0 rows (128 bf16).
// io: h1b rows (512 bf16) — skip in, result out, in place. relu fused.
// Per edge: k loaded once, 4 dots, 4 butterflies interleaved (4 indep dep-chains).
__global__ __launch_bounds__(256) void gather4_kernel(
    const ushort* __restrict__ Qb, const ushort* __restrict__ Kb,
    const int* __restrict__ rowptr, const int* __restrict__ srcs,
    ushort* __restrict__ io, float scale, int n)
{
    int i = blockIdx.x * 4 + (threadIdx.x >> 6);
    int lane = threadIdx.x & 63;
    if (i >= n) return;
    const uint* Qu = (const uint*)Qb;        // row stride 128 uints per head-buffer
    const uint* Ku = (const uint*)Kb;        // row stride 64 uints

    float q0[4], q1[4];
#pragma unroll
    for (int h = 0; h < 4; ++h) {
        uint qv = Qu[((size_t)h * NN + i) * 128 + lane];
        q0[h] = b2f((ushort)qv); q1[h] = b2f((ushort)(qv >> 16));
    }
    int p0 = rowptr[i], p1 = rowptr[i + 1];
    float den[4] = {0.f, 0.f, 0.f, 0.f};
    float o0[4] = {0.f, 0.f, 0.f, 0.f};
    float o1[4] = {0.f, 0.f, 0.f, 0.f};
    int sn = (p0 < p1) ? srcs[p0] : 0;
    for (int p = p0; p < p1; ++p) {
        int s = sn;
        sn = (p + 1 < p1) ? srcs[p + 1] : 0;              // prefetch next src index
        uint kv = Ku[(size_t)s * 64 + lane];
        uint vv[4];
#pragma unroll
        for (int h = 0; h < 4; ++h)
            vv[h] = Qu[((size_t)h * NN + s) * 128 + 64 + lane];
        float k0 = b2f((ushort)kv), k1 = b2f((ushort)(kv >> 16));
        float d[4];
#pragma unroll
        for (int h = 0; h < 4; ++h) d[h] = q0[h] * k0 + q1[h] * k1;
#pragma unroll
        for (int off = 32; off > 0; off >>= 1) {
#pragma unroll
            for (int h = 0; h < 4; ++h) d[h] += __shfl_xor(d[h], off, 64);
        }
#pragma unroll
        for (int h = 0; h < 4; ++h) {
            float e = __expf(d[h] * scale);
            den[h] += e;
            o0[h] += e * b2f((ushort)vv[h]);
            o1[h] += e * b2f((ushort)(vv[h] >> 16));
        }
    }
#pragma unroll
    for (int h = 0; h < 4; ++h) {
        uint sk = ((const uint*)io)[(size_t)i * 256 + h * 64 + lane];
        float inv = 1.0f / (den[h] + 1e-16f);
        float r0 = fmaxf(b2f((ushort)sk) + o0[h] * inv, 0.f);
        float r1 = fmaxf(b2f((ushort)(sk >> 16)) + o1[h] * inv, 0.f);
        ushort2 o; o.x = f2b(r0); o.y = f2b(r1);
        ((ushort2*)io)[(size_t)i * 256 + h * 64 + lane] = o;
    }
}

// ================= conv2 gather (single head, q|k|v rows ld=384, ILP-2) =================
__global__ __launch_bounds__(256) void edge_gather_kernel(
    const ushort* __restrict__ qkv,
    const int* __restrict__ rowptr, const int* __restrict__ srcs,
    const ushort* __restrict__ skip,
    ushort* __restrict__ outp, float scale, int n)
{
    int i = blockIdx.x * 4 + (threadIdx.x >> 6);
    int lane = threadIdx.x & 63;
    if (i >= n) return;
    const uint* Qu = (const uint*)qkv;       // row stride 192 uints

    uint sk = ((const uint*)skip)[(size_t)i * 64 + lane];
    uint qv = Qu[(size_t)i * 192 + lane];
    float q0 = b2f((ushort)qv), q1 = b2f((ushort)(qv >> 16));
    int p0 = rowptr[i], p1 = rowptr[i + 1];
    float den = 0.f, o0 = 0.f, o1 = 0.f;
    int p = p0;
    for (; p + 2 <= p1; p += 2) {
        int s0 = srcs[p], s1 = srcs[p + 1];
        const uint* kr0 = Qu + (size_t)s0 * 192 + 64;
        const uint* kr1 = Qu + (size_t)s1 * 192 + 64;
        uint kv0 = kr0[lane], vv0 = kr0[lane + 64];
        uint kv1 = kr1[lane], vv1 = kr1[lane + 64];
        float d0 = q0 * b2f((ushort)kv0) + q1 * b2f((ushort)(kv0 >> 16));
        float d1 = q0 * b2f((ushort)kv1) + q1 * b2f((ushort)(kv1 >> 16));
#pragma unroll
        for (int off = 32; off > 0; off >>= 1) {
            d0 += __shfl_xor(d0, off, 64);
            d1 += __shfl_xor(d1, off, 64);
        }
        float e0 = __expf(d0 * scale), e1 = __expf(d1 * scale);
        den += e0 + e1;
        o0 += e0 * b2f((ushort)vv0) + e1 * b2f((ushort)vv1);
        o1 += e0 * b2f((ushort)(vv0 >> 16)) + e1 * b2f((ushort)(vv1 >> 16));
    }
    if (p < p1) {
        int s = srcs[p];
        const uint* kr = Qu + (size_t)s * 192 + 64;
        uint kv = kr[lane], vv = kr[lane + 64];
        float d = q0 * b2f((ushort)kv) + q1 * b2f((ushort)(kv >> 16));
#pragma unroll
        for (int off = 32; off > 0; off >>= 1) d += __shfl_xor(d, off, 64);
        float e = __expf(d * scale);
        den += e;
        o0 += e * b2f((ushort)vv);
        o1 += e * b2f((ushort)(vv >> 16));
    }
    float inv = 1.0f / (den + 1e-16f);
    float r0 = b2f((ushort)sk) + o0 * inv;
    float r1 = b2f((ushort)(sk >> 16)) + o1 * inv;
    ushort2 o; o.x = f2b(r0); o.y = f2b(r1);
    ((ushort2*)outp)[(size_t)i * 64 + lane] = o;
}

// ================= pool over bf16 h2: run-length partial sums (+fused relu) =================
__global__ __launch_bounds__(256) void pool_kernel(
    const ushort* __restrict__ h, const int* __restrict__ batch,
    float* __restrict__ gsum, float* __restrict__ cnt, int n)
{
    int wave = threadIdx.x >> 6, lane = threadIdx.x & 63;
    int start = blockIdx.x * 256 + wave * 64;
    int end = min(start + 64, n);
    if (start >= end) return;
    int cur = batch[start];
    float a0 = 0.f, a1 = 0.f;
    int run = 0;
    for (int node = start; node < end; ++node) {
        int g = batch[node];
        if (g != cur) {
            atomicAdd(&gsum[cur * HH + 2 * lane], a0);
            atomicAdd(&gsum[cur * HH + 2 * lane + 1], a1);
            if (lane == 0) atomicAdd(&cnt[cur], (float)run);
            cur = g; a0 = a1 = 0.f; run = 0;
        }
        uint x = ((const uint*)h)[(size_t)node * 64 + lane];
        a0 += fmaxf(b2f((ushort)x), 0.f);
        a1 += fmaxf(b2f((ushort)(x >> 16)), 0.f);
        ++run;
    }
    atomicAdd(&gsum[cur * HH + 2 * lane], a0);
    atomicAdd(&gsum[cur * HH + 2 * lane + 1], a1);
    if (lane == 0) atomicAdd(&cnt[cur], (float)run);
}

__global__ void pool_fin_kernel(const float* __restrict__ gsum,
                                const float* __restrict__ cnt, float* __restrict__ g)
{
    int i = blockIdx.x * blockDim.x + threadIdx.x;
    if (i < BB * HH) g[i] = gsum[i] / fmaxf(cnt[i / HH], 1.0f);
}

// ================= output heads =================
__global__ void out_heads_kernel(
    const float* __restrict__ g,
    const float* __restrict__ w0, const float* __restrict__ b0,
    const float* __restrict__ w1, const float* __restrict__ b1,
    const float* __restrict__ w2, const float* __restrict__ b2,
    const float* __restrict__ w3, const float* __restrict__ b3,
    const float* __restrict__ w4, const float* __restrict__ b4,
    const float* __restrict__ w5, const float* __restrict__ b5,
    const float* __restrict__ w6, const float* __restrict__ b6,
    float* __restrict__ out, int total)
{
    int t = blockIdx.x * blockDim.x + threadIdx.x;
    if (t >= total) return;
    const float* W; const float* bias; int cols; int local;
    if      (t < 64)    { W = w0; bias = b0; cols = 1;   local = t; }
    else if (t < 320)   { W = w1; bias = b1; cols = 4;   local = t - 64; }
    else if (t < 512)   { W = w2; bias = b2; cols = 3;   local = t - 320; }
    else if (t < 33280) { W = w3; bias = b3; cols = SS;  local = t - 512; }
    else if (t < 66048) { W = w4; bias = b4; cols = SS;  local = t - 33280; }
    else if (t < 98816) { W = w5; bias = b5; cols = SS;  local = t - 66048; }
    else                { W = w6; bias = b6; cols = LCC; local = t - 98816; }
    int b = local / cols, c = local % cols;
    const float* gr = g + b * HH;
    float acc = bias[c];
#pragma unroll 8
    for (int i = 0; i < HH; ++i) acc += gr[i] * W[i * cols + c];
    out[t] = acc;
}

// ================= orchestration =================
extern "C" void kernel_launch(void* const* d_in, const int* in_sizes, int n_in,
                              void* d_out, int out_size, void* d_ws, size_t ws_size,
                              hipStream_t stream)
{
    (void)in_sizes; (void)n_in; (void)out_size; (void)ws_size;

    const float* nf   = (const float*)d_in[0];
    const int*   ei   = (const int*)d_in[1];
    const int*   src  = ei;
    const int*   dst  = ei + EE;
    const int*   batch= (const int*)d_in[2];
    const float* Wp   = (const float*)d_in[3];
    const float* bp   = (const float*)d_in[4];
    const float* Wq1  = (const float*)d_in[5];
    const float* bq1  = (const float*)d_in[6];
    const float* Wk1  = (const float*)d_in[7];
    const float* bk1  = (const float*)d_in[8];
    const float* Wv1  = (const float*)d_in[9];
    const float* bv1  = (const float*)d_in[10];
    const float* Ws1  = (const float*)d_in[11];
    const float* bs1  = (const float*)d_in[12];
    const float* Wq2  = (const float*)d_in[13];
    const float* bq2  = (const float*)d_in[14];
    const float* Wk2  = (const float*)d_in[15];
    const float* bk2  = (const float*)d_in[16];
    const float* Wv2  = (const float*)d_in[17];
    const float* bv2  = (const float*)d_in[18];
    const float* Ws2  = (const float*)d_in[19];
    const float* bs2  = (const float*)d_in[20];
    const float* crW  = (const float*)d_in[21];
    const float* crb  = (const float*)d_in[22];
    const float* hlW  = (const float*)d_in[23];
    const float* hlb  = (const float*)d_in[24];
    const float* mtW  = (const float*)d_in[25];
    const float* mtb  = (const float*)d_in[26];
    const float* p1W  = (const float*)d_in[27];
    const float* p1b  = (const float*)d_in[28];
    const float* p2W  = (const float*)d_in[29];
    const float* p2b  = (const float*)d_in[30];
    const float* dtW  = (const float*)d_in[31];
    const float* dtb  = (const float*)d_in[32];
    const float* slW  = (const float*)d_in[33];
    const float* slb  = (const float*)d_in[34];
    float* out = (float*)d_out;

    (void)bk1;   // bk1 contributes only a per-dst-constant score shift (cancels in softmax)

    // ---- workspace layout (~167 MB; r14-proven) ----
    ushort* Qbase  = (ushort*)d_ws;                        // N*1024 (4 x [u|v] head buffers)
    ushort* nfb    = Qbase;
    ushort* h2sb   = Qbase;                                // N*128
    ushort* qkvO   = Qbase + (size_t)NN * 256;             // N*384
    ushort* h2     = Qbase + (size_t)NN * 640;             // N*128
    ushort* h0b    = Qbase + (size_t)NN * 1024;            // N*128
    ushort* h1b    = h0b + (size_t)NN * 128;               // N*512 (conv1 skip AND out, in-place)
    ushort* wt     = h1b + (size_t)NN * 512;               // prepped weights
    float*  bb     = (float*)(wt + WTOTAL);                // fused biases
    int*    rowptr = (int*)(bb + BTOT);                    // N+1
    int*    srcs   = rowptr + NN + 1;                      // E
    int*    cnt    = srcs + EE;                            // N   (zeroed together with gsum/cntb)
    float*  gsum   = (float*)(cnt + NN);                   // B*128
    float*  cntb   = gsum + BB * HH;                       // B
    int*    cursor = (int*)(cntb + BB);                    // N
    float*  gbuf   = (float*)(cursor + NN);                // B*128

    const float scale = 0.08838834764831845f; // 1/sqrt(128)
    const dim3 blk(256);
    const int gy  = (NN + BM - 1) / BM;         // 391 row-blocks
    const int gyp = ((gy + 7) / 8) * 8;         // 392 (XCD-padded)

    // 1) weight prep + bilinear M/r composition
    wprep_kernel<<<(WTOTAL + BTOT + 255) / 256, blk, 0, stream>>>(
        Wp, Wq1, Wk1, Wv1, Ws1, Wq2, Wk2, Wv2, Ws2,
        bs1, bv1, bs2, bq2, bk2, bv2, wt, bb);
    mcomp_kernel<<<(HEADS * 128 * 128 + HEADS * 128 + 255) / 256, blk, 0, stream>>>(
        Wq1, Wk1, bq1, wt, bb);

    // 2) nf -> bf16
    f32_to_bf16_kernel<<<((NN * FF / 4) + 255) / 256, blk, 0, stream>>>(
        (const float4*)nf, (ushort4*)nfb, NN * FF / 4);

    // 3) CSR build: fill(cnt|gsum|cntb) -> hist -> single-block scan -> bucket
    fill_kernel<<<(NN + BB * HH + BB + 255) / 256, blk, 0, stream>>>(
        (unsigned*)cnt, 0u, NN + BB * HH + BB);
    hist_kernel<<<(EE + 255) / 256, blk, 0, stream>>>(dst, cnt, EE);
    scan_kernel<<<1, SCT, 0, stream>>>(cnt, rowptr, cursor, NN);
    bucket_kernel<<<(EE + 255) / 256, blk, 0, stream>>>(src, dst, cursor, srcs, EE);

    // 4) proj: h0b = relu(nf @ Wp + bp)   (mode 0, gx=1, K=64)
    gemm_bf16<<<dim3(1 * gyp), blk, 0, stream>>>(
        nfb, wt, bp, h0b, HH, h0b, 0, NN, FF, 1, 1, gy);

    // 5) F1-mega: [skip(512)->h1b | per head u|v -> Qbase+h*N*256]   (mode 1, gx=12, K=128)
    gemm_bf16<<<dim3(12 * gyp), blk, 0, stream>>>(
        h0b, wt + F1OFF, bb, h1b, 512, Qbase, 1, NN, HH, 0, 12, gy);

    // 6) fused 4-head gather (one wave per node; k = h0, shared)
    gather4_kernel<<<(NN + 3) / 4, blk, 0, stream>>>(
        Qbase, h0b, rowptr, srcs, h1b, scale, NN);

    // 7) F2: [skip(128)->h2sb | qkv(384)->qkvO]   (mode 2, gx=4, K=512)
    gemm_bf16<<<dim3(4 * gyp), blk, 0, stream>>>(
        h1b, wt + F2OFF, bb + 1536, h2sb, 128, qkvO, 2, NN, 4 * HH, 0, 4, gy);

    // 8) gather conv2 (single head)
    edge_gather_kernel<<<(NN + 3) / 4, blk, 0, stream>>>(
        qkvO, rowptr, srcs, h2sb, h2, scale, NN);

    // 9) pool (relu fused, bf16 input) + finalize
    pool_kernel<<<(NN + 255) / 256, blk, 0, stream>>>(h2, batch, gsum, cntb, NN);
    pool_fin_kernel<<<(BB * HH + 255) / 256, blk, 0, stream>>>(gsum, cntb, gbuf);

    // 10) output heads
    const int total = BB * (1 + 4 + 3 + SS + SS + SS + LCC);
    out_heads_kernel<<<(total + 255) / 256, blk, 0, stream>>>(
        gbuf, crW, crb, hlW, hlb, mtW, mtb, p1W, p1b, p2W, p2b, dtW, dtb, slW, slb, out, total);
}

// Round 16
// 379.164 us; speedup vs baseline: 1.2682x; 1.2682x over previous
//
#include <hip/hip_runtime.h>

#define NN 50000
#define EE 100000
#define FF 64
#define HH 128
#define HEADS 4
#define BB 64
#define SS 512
#define LCC 8

// ---- bf16 helpers ----
__device__ __forceinline__ float b2f(ushort u) {
    return __uint_as_float(((unsigned)u) << 16);
}
__device__ __forceinline__ ushort f2b(float f) {
    unsigned u = __float_as_uint(f);
    unsigned r = (u + 0x7FFFu + ((u >> 16) & 1u)) >> 16;   // RNE
    return (ushort)r;
}

typedef __attribute__((ext_vector_type(4))) float f32x4;
typedef __attribute__((ext_vector_type(8))) short s16x8;
typedef __attribute__((ext_vector_type(8))) ushort u16x8;

__device__ __forceinline__ void glls16(const ushort* g, ushort* l) {
    __builtin_amdgcn_global_load_lds((const __attribute__((address_space(1))) void*)g,
                                     (__attribute__((address_space(3))) void*)l, 16, 0, 0);
}

// ================= bf16 MFMA GEMM (r12-proven core) =================
#define BM 128
#define BN 128
#define BK 64
#define EST 68   // epilogue staging stride (f32) — breaks power-of-2 bank aliasing

__global__ __launch_bounds__(256) void gemm_bf16(
    const ushort* __restrict__ A, const ushort* __restrict__ Bt,
    const float* __restrict__ bias,
    ushort* __restrict__ C1, int ld1,
    ushort* __restrict__ C2b, int mode,
    int M, int K, int relu, int gx, int gy)
{
    __shared__ __align__(16) ushort Sm[2 * BM * BK];   // 32 KB: As | Bs, reused by epilogue
    ushort* As = Sm;
    ushort* Bs = Sm + BM * BK;

    const int bid  = blockIdx.x;
    const int xcd  = bid & 7;
    const int slot = bid >> 3;
    const int bx   = slot % gx;
    const int by   = xcd + 8 * (slot / gx);
    if (by >= gy) return;
    const int m0 = by * BM;
    const int n0 = bx * BN;

    const int t = threadIdx.x;
    const int lane = t & 63;
    const int wave = t >> 6;
    const int wm = (wave & 1) * 64;
    const int wn = (wave >> 1) * 64;
    const int lrow = lane & 15;
    const int g    = lane >> 4;

    const int srow = (wave << 5) + (lane >> 3);
    const int scs  = lane & 7;

    const ushort* ga[4];
    const ushort* gb[4];
#pragma unroll
    for (int p = 0; p < 4; ++p) {
        const int row = srow + (p << 3);
        const int l   = scs ^ (row & 7);
        ga[p] = A + (size_t)min(m0 + row, M - 1) * K + (l << 3);
        gb[p] = Bt + (size_t)(n0 + row) * K + (l << 3);
    }
    const int ldsoff = (wave << 11);

    f32x4 acc[4][4] = {};

    for (int k0 = 0; k0 < K; k0 += BK) {
#pragma unroll
        for (int p = 0; p < 4; ++p) glls16(ga[p] + k0, As + ldsoff + (p << 9));
#pragma unroll
        for (int p = 0; p < 4; ++p) glls16(gb[p] + k0, Bs + ldsoff + (p << 9));
        __syncthreads();

#pragma unroll
        for (int kk = 0; kk < 2; ++kk) {
            s16x8 af[4], bf[4];
#pragma unroll
            for (int i = 0; i < 4; ++i) {
                const int R = wm + i * 16 + lrow;
                const int c = ((kk << 2) + g) ^ (R & 7);
                af[i] = *(const s16x8*)&As[(R << 6) + (c << 3)];
            }
#pragma unroll
            for (int j = 0; j < 4; ++j) {
                const int R = wn + j * 16 + lrow;
                const int c = ((kk << 2) + g) ^ (R & 7);
                bf[j] = *(const s16x8*)&Bs[(R << 6) + (c << 3)];
            }
#pragma unroll
            for (int i = 0; i < 4; ++i)
#pragma unroll
                for (int j = 0; j < 4; ++j)
                    acc[i][j] = __builtin_amdgcn_mfma_f32_16x16x32_bf16(af[i], bf[j], acc[i][j], 0, 0, 0);
        }
        __syncthreads();
    }

    // ---- LDS-staged epilogue ----
    float* Es = (float*)Sm + wave * (16 * EST);

    const int wbase = n0 + wn;
    ushort* Cw; int ldw, cb;
    if (mode == 0) { Cw = C1; ldw = ld1; cb = wbase; }
    else if (mode == 1) {
        if (wbase < 512) { Cw = C1; ldw = ld1; cb = wbase; }
        else {
            const int u = wbase - 512;
            const int h = u >> 8;                // 256 cols per head: u(128) | v(128)
            cb = u & 255;
            Cw = C2b + (size_t)h * NN * 256; ldw = 256;
        }
    } else {
        if (wbase < 128) { Cw = C1; ldw = 128; cb = wbase; }
        else             { Cw = C2b; ldw = 384; cb = wbase - 128; }
    }

    float bj[4];
#pragma unroll
    for (int j = 0; j < 4; ++j) bj[j] = bias[wbase + j * 16 + lrow];

    const int rbase = (lane >> 4) * 4;
    const int rrow  = lane >> 2;
    const int rcol  = (lane & 3) << 4;

#pragma unroll
    for (int i = 0; i < 4; ++i) {
#pragma unroll
        for (int j = 0; j < 4; ++j)
#pragma unroll
            for (int r = 0; r < 4; ++r) {
                float v = acc[i][j][r] + bj[j];
                if (relu) v = fmaxf(v, 0.f);
                Es[(rbase + r) * EST + j * 16 + lrow] = v;
            }
        const int gm = m0 + wm + i * 16 + rrow;
        if (gm < M) {
            const float* src = Es + rrow * EST + rcol;
            f32x4 f0 = *(const f32x4*)(src + 0);
            f32x4 f1 = *(const f32x4*)(src + 4);
            f32x4 f2 = *(const f32x4*)(src + 8);
            f32x4 f3 = *(const f32x4*)(src + 12);
            u16x8 o0, o1;
            o0[0] = f2b(f0[0]); o0[1] = f2b(f0[1]); o0[2] = f2b(f0[2]); o0[3] = f2b(f0[3]);
            o0[4] = f2b(f1[0]); o0[5] = f2b(f1[1]); o0[6] = f2b(f1[2]); o0[7] = f2b(f1[3]);
            o1[0] = f2b(f2[0]); o1[1] = f2b(f2[1]); o1[2] = f2b(f2[2]); o1[3] = f2b(f2[3]);
            o1[4] = f2b(f3[0]); o1[5] = f2b(f3[1]); o1[6] = f2b(f3[2]); o1[7] = f2b(f3[3]);
            ushort* dst = Cw + (size_t)gm * ldw + cb + rcol;
            *(u16x8*)(dst + 0) = o0;
            *(u16x8*)(dst + 8) = o1;
        }
    }
}

// ================= weight prep =================
#define F1OFF  8192
#define F2OFF  204800
#define WTOTAL 466944
#define BTOT   2048

__global__ void wprep_kernel(
    const float* __restrict__ Wp,
    const float* __restrict__ Wq1, const float* __restrict__ Wk1,
    const float* __restrict__ Wv1, const float* __restrict__ Ws1,
    const float* __restrict__ Wq2, const float* __restrict__ Wk2,
    const float* __restrict__ Wv2, const float* __restrict__ Ws2,
    const float* __restrict__ bs1, const float* __restrict__ bv1,
    const float* __restrict__ bs2,
    const float* __restrict__ bq2, const float* __restrict__ bk2, const float* __restrict__ bv2,
    ushort* __restrict__ wt, float* __restrict__ bb)
{
    int t = blockIdx.x * 256 + threadIdx.x;
    if (t < WTOTAL) {
        float v;
        if (t < F1OFF) {
            int n = t >> 6, k = t & 63;
            v = Wp[k * 128 + n];
        } else if (t < F2OFF) {
            int u = t - F1OFF;
            int n = u >> 7, k = u & 127;
            if (n < 512) v = Ws1[k * 512 + n];
            else {
                int r = n - 512;
                int h = r >> 8, c = r & 255;
                if (c < 128) return;             // u (M) rows: filled by mcomp_kernel
                v = Wv1[k * 512 + h * 128 + (c - 128)];
            }
        } else {
            int u = t - F2OFF;
            int n = u >> 9, k = u & 511;
            if (n < 128) v = Ws2[k * 128 + n];
            else {
                int r = n - 128;
                const float* W = (r < 128) ? Wq2 : (r < 256) ? Wk2 : Wv2;
                v = W[k * 128 + (r & 127)];
            }
        }
        wt[t] = f2b(v);
    } else if (t < WTOTAL + BTOT) {
        int u = t - WTOTAL;
        float v;
        if (u < 512) v = bs1[u];
        else if (u < 1536) {
            int r = u - 512;
            int h = r >> 8, c = r & 255;
            if (c < 128) return;                 // r_h bias: filled by mcomp_kernel
            v = bv1[h * 128 + (c - 128)];
        } else {
            int c = u - 1536;
            v = (c < 128) ? bs2[c]
              : (c < 256) ? bq2[c - 128]
              : (c < 384) ? bk2[c - 256] : bv2[c - 384];
        }
        bb[u] = v;
    }
}

// ================= mcomp: per-head M = Wq Wk^T (bf16) and r = Wk bq (fp32 bias) ====
__global__ void mcomp_kernel(
    const float* __restrict__ Wq1, const float* __restrict__ Wk1,
    const float* __restrict__ bq1, ushort* __restrict__ wt, float* __restrict__ bb)
{
    int t = blockIdx.x * 256 + threadIdx.x;
    if (t < HEADS * 128 * 128) {
        int h = t >> 14;
        int rem = t & 16383;
        int b = rem >> 7, a = rem & 127;
        const float* wq = Wq1 + a * 512 + h * 128;
        const float* wk = Wk1 + b * 512 + h * 128;
        float acc = 0.f;
#pragma unroll 8
        for (int d = 0; d < 128; ++d) acc += wq[d] * wk[d];
        wt[F1OFF + (size_t)(512 + h * 256 + b) * 128 + a] = f2b(acc);
    } else if (t < HEADS * 128 * 128 + HEADS * 128) {
        int u = t - HEADS * 128 * 128;
        int h = u >> 7, b = u & 127;
        const float* wk = Wk1 + b * 512 + h * 128;
        const float* bq = bq1 + h * 128;
        float acc = 0.f;
#pragma unroll 8
        for (int d = 0; d < 128; ++d) acc += wk[d] * bq[d];
        bb[512 + h * 256 + b] = acc;
    }
}

// ================= fp32 -> bf16 (x4) =================
__global__ void f32_to_bf16_kernel(const float4* __restrict__ in, ushort4* __restrict__ out, int n4)
{
    int i = blockIdx.x * 256 + threadIdx.x;
    if (i >= n4) return;
    float4 v = in[i];
    ushort4 o;
    o.x = f2b(v.x); o.y = f2b(v.y); o.z = f2b(v.z); o.w = f2b(v.w);
    out[i] = o;
}

__global__ void fill_kernel(unsigned* __restrict__ p, unsigned v, int n) {
    int i = blockIdx.x * blockDim.x + threadIdx.x;
    if (i < n) p[i] = v;
}

// ================= CSR build (dst -> src list) — r14-proven 3-dispatch scan =================
__global__ void hist_kernel(const int* __restrict__ dst, int* __restrict__ cnt, int E) {
    int e = blockIdx.x * 256 + threadIdx.x;
    if (e < E) atomicAdd(&cnt[dst[e]], 1);
}

#define SCAN_B 1024
__global__ void scan_bsum_kernel(const int* __restrict__ cnt, int* __restrict__ bsum, int n) {
    __shared__ int sd[256];
    int tid = threadIdx.x;
    int base = blockIdx.x * SCAN_B + tid * 4;
    int s = 0;
#pragma unroll
    for (int j = 0; j < 4; ++j) if (base + j < n) s += cnt[base + j];
    sd[tid] = s;
    __syncthreads();
    for (int off = 128; off > 0; off >>= 1) {
        if (tid < off) sd[tid] += sd[tid + off];
        __syncthreads();
    }
    if (tid == 0) bsum[blockIdx.x] = sd[0];
}

__global__ void scan_excl_kernel(int* __restrict__ bsum, int nb) {
    if (threadIdx.x == 0 && blockIdx.x == 0) {
        int acc = 0;
        for (int i = 0; i < nb; ++i) { int v = bsum[i]; bsum[i] = acc; acc += v; }
    }
}

__global__ void scan_final_kernel(const int* __restrict__ cnt, const int* __restrict__ bsum,
                                  int* __restrict__ rowptr, int* __restrict__ cursor, int n) {
    __shared__ int sd[256];
    int tid = threadIdx.x;
    int base = blockIdx.x * SCAN_B + tid * 4;
    int v[4]; int s = 0;
#pragma unroll
    for (int j = 0; j < 4; ++j) { v[j] = (base + j < n) ? cnt[base + j] : 0; s += v[j]; }
    sd[tid] = s;
    __syncthreads();
    for (int off = 1; off < 256; off <<= 1) {
        int t2 = (tid >= off) ? sd[tid - off] : 0;
        __syncthreads();
        sd[tid] += t2;
        __syncthreads();
    }
    int acc = bsum[blockIdx.x] + sd[tid] - s;
#pragma unroll
    for (int j = 0; j < 4; ++j) {
        if (base + j < n) cursor[base + j] = acc;
        acc += v[j];
        if (base + j < n) rowptr[base + j + 1] = acc;
    }
    if (blockIdx.x == 0 && tid == 0) rowptr[0] = 0;
}

__global__ void bucket_kernel(const int* __restrict__ src, const int* __restrict__ dst,
                              int* __restrict__ cursor, int* __restrict__ srcs, int E) {
    int e = blockIdx.x * 256 + threadIdx.x;
    if (e >= E) return;
    int p = atomicAdd(&cursor[dst[e]], 1);
    srcs[p] = src[e];
}

// ================= conv1 gather: ALL 4 HEADS per wave (one wave per node) =================
// Qb: 4 head buffers (stride NN*256 us), row = [u(128)|v(128)]. Kb = h0 rows (128 bf16).
// io: h1b rows (512 bf16) — skip in, result out, in place. relu fused.
__global__ __launch_bounds__(256) void gather4_kernel(
    const ushort* __restrict__ Qb, const ushort* __restrict__ Kb,
    const int* __restrict__ rowptr, const int* __restrict__ srcs,
    ushort* __restrict__ io, float scale, int n)
{
    int i = blockIdx.x * 4 + (threadIdx.x >> 6);
    int lane = threadIdx.x & 63;
    if (i >= n) return;
    const uint* Qu = (const uint*)Qb;        // row stride 128 uints per head-buffer
    const uint* Ku = (const uint*)Kb;        // row stride 64 uints

    float q0[4], q1[4];
#pragma unroll
    for (int h = 0; h < 4; ++h) {
        uint qv = Qu[((size_t)h * NN + i) * 128 + lane];
        q0[h] = b2f((ushort)qv); q1[h] = b2f((ushort)(qv >> 16));
    }
    int p0 = rowptr[i], p1 = rowptr[i + 1];
    float den[4] = {0.f, 0.f, 0.f, 0.f};
    float o0[4] = {0.f, 0.f, 0.f, 0.f};
    float o1[4] = {0.f, 0.f, 0.f, 0.f};
    int sn = (p0 < p1) ? srcs[p0] : 0;
    for (int p = p0; p < p1; ++p) {
        int s = sn;
        sn = (p + 1 < p1) ? srcs[p + 1] : 0;              // prefetch next src index
        uint kv = Ku[(size_t)s * 64 + lane];
        uint vv[4];
#pragma unroll
        for (int h = 0; h < 4; ++h)
            vv[h] = Qu[((size_t)h * NN + s) * 128 + 64 + lane];
        float k0 = b2f((ushort)kv), k1 = b2f((ushort)(kv >> 16));
        float d[4];
#pragma unroll
        for (int h = 0; h < 4; ++h) d[h] = q0[h] * k0 + q1[h] * k1;
#pragma unroll
        for (int off = 32; off > 0; off >>= 1) {
#pragma unroll
            for (int h = 0; h < 4; ++h) d[h] += __shfl_xor(d[h], off, 64);
        }
#pragma unroll
        for (int h = 0; h < 4; ++h) {
            float e = __expf(d[h] * scale);
            den[h] += e;
            o0[h] += e * b2f((ushort)vv[h]);
            o1[h] += e * b2f((ushort)(vv[h] >> 16));
        }
    }
#pragma unroll
    for (int h = 0; h < 4; ++h) {
        uint sk = ((const uint*)io)[(size_t)i * 256 + h * 64 + lane];
        float inv = 1.0f / (den[h] + 1e-16f);
        float r0 = fmaxf(b2f((ushort)sk) + o0[h] * inv, 0.f);
        float r1 = fmaxf(b2f((ushort)(sk >> 16)) + o1[h] * inv, 0.f);
        ushort2 o; o.x = f2b(r0); o.y = f2b(r1);
        ((ushort2*)io)[(size_t)i * 256 + h * 64 + lane] = o;
    }
}

// ================= conv2 gather (single head, q|k|v rows ld=384, ILP-2) =================
__global__ __launch_bounds__(256) void edge_gather_kernel(
    const ushort* __restrict__ qkv,
    const int* __restrict__ rowptr, const int* __restrict__ srcs,
    const ushort* __restrict__ skip,
    ushort* __restrict__ outp, float scale, int n)
{
    int i = blockIdx.x * 4 + (threadIdx.x >> 6);
    int lane = threadIdx.x & 63;
    if (i >= n) return;
    const uint* Qu = (const uint*)qkv;       // row stride 192 uints

    uint sk = ((const uint*)skip)[(size_t)i * 64 + lane];
    uint qv = Qu[(size_t)i * 192 + lane];
    float q0 = b2f((ushort)qv), q1 = b2f((ushort)(qv >> 16));
    int p0 = rowptr[i], p1 = rowptr[i + 1];
    float den = 0.f, o0 = 0.f, o1 = 0.f;
    int p = p0;
    for (; p + 2 <= p1; p += 2) {
        int s0 = srcs[p], s1 = srcs[p + 1];
        const uint* kr0 = Qu + (size_t)s0 * 192 + 64;
        const uint* kr1 = Qu + (size_t)s1 * 192 + 64;
        uint kv0 = kr0[lane], vv0 = kr0[lane + 64];
        uint kv1 = kr1[lane], vv1 = kr1[lane + 64];
        float d0 = q0 * b2f((ushort)kv0) + q1 * b2f((ushort)(kv0 >> 16));
        float d1 = q0 * b2f((ushort)kv1) + q1 * b2f((ushort)(kv1 >> 16));
#pragma unroll
        for (int off = 32; off > 0; off >>= 1) {
            d0 += __shfl_xor(d0, off, 64);
            d1 += __shfl_xor(d1, off, 64);
        }
        float e0 = __expf(d0 * scale), e1 = __expf(d1 * scale);
        den += e0 + e1;
        o0 += e0 * b2f((ushort)vv0) + e1 * b2f((ushort)vv1);
        o1 += e0 * b2f((ushort)(vv0 >> 16)) + e1 * b2f((ushort)(vv1 >> 16));
    }
    if (p < p1) {
        int s = srcs[p];
        const uint* kr = Qu + (size_t)s * 192 + 64;
        uint kv = kr[lane], vv = kr[lane + 64];
        float d = q0 * b2f((ushort)kv) + q1 * b2f((ushort)(kv >> 16));
#pragma unroll
        for (int off = 32; off > 0; off >>= 1) d += __shfl_xor(d, off, 64);
        float e = __expf(d * scale);
        den += e;
        o0 += e * b2f((ushort)vv);
        o1 += e * b2f((ushort)(vv >> 16));
    }
    float inv = 1.0f / (den + 1e-16f);
    float r0 = b2f((ushort)sk) + o0 * inv;
    float r1 = b2f((ushort)(sk >> 16)) + o1 * inv;
    ushort2 o; o.x = f2b(r0); o.y = f2b(r1);
    ((ushort2*)outp)[(size_t)i * 64 + lane] = o;
}

// ================= pool over bf16 h2: run-length partial sums (+fused relu) =================
__global__ __launch_bounds__(256) void pool_kernel(
    const ushort* __restrict__ h, const int* __restrict__ batch,
    float* __restrict__ gsum, float* __restrict__ cnt, int n)
{
    int wave = threadIdx.x >> 6, lane = threadIdx.x & 63;
    int start = blockIdx.x * 256 + wave * 64;
    int end = min(start + 64, n);
    if (start >= end) return;
    int cur = batch[start];
    float a0 = 0.f, a1 = 0.f;
    int run = 0;
    for (int node = start; node < end; ++node) {
        int g = batch[node];
        if (g != cur) {
            atomicAdd(&gsum[cur * HH + 2 * lane], a0);
            atomicAdd(&gsum[cur * HH + 2 * lane + 1], a1);
            if (lane == 0) atomicAdd(&cnt[cur], (float)run);
            cur = g; a0 = a1 = 0.f; run = 0;
        }
        uint x = ((const uint*)h)[(size_t)node * 64 + lane];
        a0 += fmaxf(b2f((ushort)x), 0.f);
        a1 += fmaxf(b2f((ushort)(x >> 16)), 0.f);
        ++run;
    }
    atomicAdd(&gsum[cur * HH + 2 * lane], a0);
    atomicAdd(&gsum[cur * HH + 2 * lane + 1], a1);
    if (lane == 0) atomicAdd(&cnt[cur], (float)run);
}

__global__ void pool_fin_kernel(const float* __restrict__ gsum,
                                const float* __restrict__ cnt, float* __restrict__ g)
{
    int i = blockIdx.x * blockDim.x + threadIdx.x;
    if (i < BB * HH) g[i] = gsum[i] / fmaxf(cnt[i / HH], 1.0f);
}

// ================= output heads =================
__global__ void out_heads_kernel(
    const float* __restrict__ g,
    const float* __restrict__ w0, const float* __restrict__ b0,
    const float* __restrict__ w1, const float* __restrict__ b1,
    const float* __restrict__ w2, const float* __restrict__ b2,
    const float* __restrict__ w3, const float* __restrict__ b3,
    const float* __restrict__ w4, const float* __restrict__ b4,
    const float* __restrict__ w5, const float* __restrict__ b5,
    const float* __restrict__ w6, const float* __restrict__ b6,
    float* __restrict__ out, int total)
{
    int t = blockIdx.x * blockDim.x + threadIdx.x;
    if (t >= total) return;
    const float* W; const float* bias; int cols; int local;
    if      (t < 64)    { W = w0; bias = b0; cols = 1;   local = t; }
    else if (t < 320)   { W = w1; bias = b1; cols = 4;   local = t - 64; }
    else if (t < 512)   { W = w2; bias = b2; cols = 3;   local = t - 320; }
    else if (t < 33280) { W = w3; bias = b3; cols = SS;  local = t - 512; }
    else if (t < 66048) { W = w4; bias = b4; cols = SS;  local = t - 33280; }
    else if (t < 98816) { W = w5; bias = b5; cols = SS;  local = t - 66048; }
    else                { W = w6; bias = b6; cols = LCC; local = t - 98816; }
    int b = local / cols, c = local % cols;
    const float* gr = g + b * HH;
    float acc = bias[c];
#pragma unroll 8
    for (int i = 0; i < HH; ++i) acc += gr[i] * W[i * cols + c];
    out[t] = acc;
}

// ================= orchestration =================
extern "C" void kernel_launch(void* const* d_in, const int* in_sizes, int n_in,
                              void* d_out, int out_size, void* d_ws, size_t ws_size,
                              hipStream_t stream)
{
    (void)in_sizes; (void)n_in; (void)out_size; (void)ws_size;

    const float* nf   = (const float*)d_in[0];
    const int*   ei   = (const int*)d_in[1];
    const int*   src  = ei;
    const int*   dst  = ei + EE;
    const int*   batch= (const int*)d_in[2];
    const float* Wp   = (const float*)d_in[3];
    const float* bp   = (const float*)d_in[4];
    const float* Wq1  = (const float*)d_in[5];
    const float* bq1  = (const float*)d_in[6];
    const float* Wk1  = (const float*)d_in[7];
    const float* bk1  = (const float*)d_in[8];
    const float* Wv1  = (const float*)d_in[9];
    const float* bv1  = (const float*)d_in[10];
    const float* Ws1  = (const float*)d_in[11];
    const float* bs1  = (const float*)d_in[12];
    const float* Wq2  = (const float*)d_in[13];
    const float* bq2  = (const float*)d_in[14];
    const float* Wk2  = (const float*)d_in[15];
    const float* bk2  = (const float*)d_in[16];
    const float* Wv2  = (const float*)d_in[17];
    const float* bv2  = (const float*)d_in[18];
    const float* Ws2  = (const float*)d_in[19];
    const float* bs2  = (const float*)d_in[20];
    const float* crW  = (const float*)d_in[21];
    const float* crb  = (const float*)d_in[22];
    const float* hlW  = (const float*)d_in[23];
    const float* hlb  = (const float*)d_in[24];
    const float* mtW  = (const float*)d_in[25];
    const float* mtb  = (const float*)d_in[26];
    const float* p1W  = (const float*)d_in[27];
    const float* p1b  = (const float*)d_in[28];
    const float* p2W  = (const float*)d_in[29];
    const float* p2b  = (const float*)d_in[30];
    const float* dtW  = (const float*)d_in[31];
    const float* dtb  = (const float*)d_in[32];
    const float* slW  = (const float*)d_in[33];
    const float* slb  = (const float*)d_in[34];
    float* out = (float*)d_out;

    (void)bk1;   // bk1 contributes only a per-dst-constant score shift (cancels in softmax)

    // ---- workspace layout (~167 MB; r14/r15-proven) ----
    ushort* Qbase  = (ushort*)d_ws;                        // N*1024 (4 x [u|v] head buffers)
    ushort* nfb    = Qbase;
    ushort* h2sb   = Qbase;                                // N*128
    ushort* qkvO   = Qbase + (size_t)NN * 256;             // N*384
    ushort* h2     = Qbase + (size_t)NN * 640;             // N*128
    ushort* h0b    = Qbase + (size_t)NN * 1024;            // N*128
    ushort* h1b    = h0b + (size_t)NN * 128;               // N*512 (conv1 skip AND out, in-place)
    ushort* wt     = h1b + (size_t)NN * 512;               // prepped weights
    float*  bb     = (float*)(wt + WTOTAL);                // fused biases
    int*    rowptr = (int*)(bb + BTOT);                    // N+1
    int*    srcs   = rowptr + NN + 1;                      // E
    int*    cnt    = srcs + EE;                            // N   (zeroed together with gsum/cntb)
    float*  gsum   = (float*)(cnt + NN);                   // B*128
    float*  cntb   = gsum + BB * HH;                       // B
    int*    cursor = (int*)(cntb + BB);                    // N
    int*    bsum   = cursor + NN;                          // 64
    float*  gbuf   = (float*)(bsum + 64);                  // B*128

    const float scale = 0.08838834764831845f; // 1/sqrt(128)
    const dim3 blk(256);
    const int gy  = (NN + BM - 1) / BM;         // 391 row-blocks
    const int gyp = ((gy + 7) / 8) * 8;         // 392 (XCD-padded)
    const int nb = (NN + SCAN_B - 1) / SCAN_B;  // 49

    // 1) weight prep + bilinear M/r composition
    wprep_kernel<<<(WTOTAL + BTOT + 255) / 256, blk, 0, stream>>>(
        Wp, Wq1, Wk1, Wv1, Ws1, Wq2, Wk2, Wv2, Ws2,
        bs1, bv1, bs2, bq2, bk2, bv2, wt, bb);
    mcomp_kernel<<<(HEADS * 128 * 128 + HEADS * 128 + 255) / 256, blk, 0, stream>>>(
        Wq1, Wk1, bq1, wt, bb);

    // 2) nf -> bf16
    f32_to_bf16_kernel<<<((NN * FF / 4) + 255) / 256, blk, 0, stream>>>(
        (const float4*)nf, (ushort4*)nfb, NN * FF / 4);

    // 3) CSR build (r14-proven parallel 3-dispatch scan)
    fill_kernel<<<(NN + BB * HH + BB + 255) / 256, blk, 0, stream>>>(
        (unsigned*)cnt, 0u, NN + BB * HH + BB);
    hist_kernel<<<(EE + 255) / 256, blk, 0, stream>>>(dst, cnt, EE);
    scan_bsum_kernel<<<nb, blk, 0, stream>>>(cnt, bsum, NN);
    scan_excl_kernel<<<1, 64, 0, stream>>>(bsum, nb);
    scan_final_kernel<<<nb, blk, 0, stream>>>(cnt, bsum, rowptr, cursor, NN);
    bucket_kernel<<<(EE + 255) / 256, blk, 0, stream>>>(src, dst, cursor, srcs, EE);

    // 4) proj: h0b = relu(nf @ Wp + bp)   (mode 0, gx=1, K=64)
    gemm_bf16<<<dim3(1 * gyp), blk, 0, stream>>>(
        nfb, wt, bp, h0b, HH, h0b, 0, NN, FF, 1, 1, gy);

    // 5) F1-mega: [skip(512)->h1b | per head u|v -> Qbase+h*N*256]   (mode 1, gx=12, K=128)
    gemm_bf16<<<dim3(12 * gyp), blk, 0, stream>>>(
        h0b, wt + F1OFF, bb, h1b, 512, Qbase, 1, NN, HH, 0, 12, gy);

    // 6) fused 4-head gather (one wave per node; k = h0, shared)
    gather4_kernel<<<(NN + 3) / 4, blk, 0, stream>>>(
        Qbase, h0b, rowptr, srcs, h1b, scale, NN);

    // 7) F2: [skip(128)->h2sb | qkv(384)->qkvO]   (mode 2, gx=4, K=512)
    gemm_bf16<<<dim3(4 * gyp), blk, 0, stream>>>(
        h1b, wt + F2OFF, bb + 1536, h2sb, 128, qkvO, 2, NN, 4 * HH, 0, 4, gy);

    // 8) gather conv2 (single head)
    edge_gather_kernel<<<(NN + 3) / 4, blk, 0, stream>>>(
        qkvO, rowptr, srcs, h2sb, h2, scale, NN);

    // 9) pool (relu fused, bf16 input) + finalize
    pool_kernel<<<(NN + 255) / 256, blk, 0, stream>>>(h2, batch, gsum, cntb, NN);
    pool_fin_kernel<<<(BB * HH + 255) / 256, blk, 0, stream>>>(gsum, cntb, gbuf);

    // 10) output heads
    const int total = BB * (1 + 4 + 3 + SS + SS + SS + LCC);
    out_heads_kernel<<<(total + 255) / 256, blk, 0, stream>>>(
        gbuf, crW, crb, hlW, hlb, mtW, mtb, p1W, p1b, p2W, p2b, dtW, dtb, slW, slb, out, total);
}

// Round 17
// 373.994 us; speedup vs baseline: 1.2857x; 1.0138x over previous
//
#include <hip/hip_runtime.h>
#include <hip/hip_bf16.h>

#define NN 50000
#define EE 100000
#define FF 64
#define HH 128
#define HEADS 4
#define BB 64
#define SS 512
#define LCC 8

// ---- bf16 helpers ----
__device__ __forceinline__ float b2f(ushort u) {
    return __uint_as_float(((unsigned)u) << 16);
}
__device__ __forceinline__ ushort f2b(float f) {
    unsigned u = __float_as_uint(f);
    unsigned r = (u + 0x7FFFu + ((u >> 16) & 1u)) >> 16;   // RNE
    return (ushort)r;
}
// packed RNE convert: 2 f32 -> 1 uint (low = a), maps to v_cvt_pk_bf16_f32
__device__ __forceinline__ uint f2b_pk(float a, float b) {
    __hip_bfloat162 h = __float22bfloat162_rn(make_float2(a, b));
    return *reinterpret_cast<uint*>(&h);
}

typedef __attribute__((ext_vector_type(4))) float f32x4;
typedef __attribute__((ext_vector_type(8))) short s16x8;
typedef __attribute__((ext_vector_type(4))) uint u32x4;

__device__ __forceinline__ void glls16(const ushort* g, ushort* l) {
    __builtin_amdgcn_global_load_lds((const __attribute__((address_space(1))) void*)g,
                                     (__attribute__((address_space(3))) void*)l, 16, 0, 0);
}

// ================= bf16 MFMA GEMM (r12-proven core + packed-cvt epilogue) =================
// C = A[M,K] @ Bt[N,K]^T + bias, bf16 out. Destination select by mode (wave-uniform):
//  mode 0: all cols -> C1 (ld1)
//  mode 1: cols<512 -> C1 (ld1); cols 512.. -> C2b (ld 1024), col-512   [UV buffer]
//  mode 2: cols<128 -> C1 (ld 128); else -> C2b (ld 384), col-128
#define BM 128
#define BN 128
#define BK 64
#define EST 68   // epilogue staging stride (f32) — breaks power-of-2 bank aliasing

__global__ __launch_bounds__(256) void gemm_bf16(
    const ushort* __restrict__ A, const ushort* __restrict__ Bt,
    const float* __restrict__ bias,
    ushort* __restrict__ C1, int ld1,
    ushort* __restrict__ C2b, int mode,
    int M, int K, int relu, int gx, int gy)
{
    __shared__ __align__(16) ushort Sm[2 * BM * BK];   // 32 KB: As | Bs, reused by epilogue
    ushort* As = Sm;
    ushort* Bs = Sm + BM * BK;

    const int bid  = blockIdx.x;
    const int xcd  = bid & 7;
    const int slot = bid >> 3;
    const int bx   = slot % gx;
    const int by   = xcd + 8 * (slot / gx);
    if (by >= gy) return;
    const int m0 = by * BM;
    const int n0 = bx * BN;

    const int t = threadIdx.x;
    const int lane = t & 63;
    const int wave = t >> 6;
    const int wm = (wave & 1) * 64;
    const int wn = (wave >> 1) * 64;
    const int lrow = lane & 15;
    const int g    = lane >> 4;

    const int srow = (wave << 5) + (lane >> 3);
    const int scs  = lane & 7;

    const ushort* ga[4];
    const ushort* gb[4];
#pragma unroll
    for (int p = 0; p < 4; ++p) {
        const int row = srow + (p << 3);
        const int l   = scs ^ (row & 7);
        ga[p] = A + (size_t)min(m0 + row, M - 1) * K + (l << 3);
        gb[p] = Bt + (size_t)(n0 + row) * K + (l << 3);
    }
    const int ldsoff = (wave << 11);

    f32x4 acc[4][4] = {};

    for (int k0 = 0; k0 < K; k0 += BK) {
#pragma unroll
        for (int p = 0; p < 4; ++p) glls16(ga[p] + k0, As + ldsoff + (p << 9));
#pragma unroll
        for (int p = 0; p < 4; ++p) glls16(gb[p] + k0, Bs + ldsoff + (p << 9));
        __syncthreads();

#pragma unroll
        for (int kk = 0; kk < 2; ++kk) {
            s16x8 af[4], bf[4];
#pragma unroll
            for (int i = 0; i < 4; ++i) {
                const int R = wm + i * 16 + lrow;
                const int c = ((kk << 2) + g) ^ (R & 7);
                af[i] = *(const s16x8*)&As[(R << 6) + (c << 3)];
            }
#pragma unroll
            for (int j = 0; j < 4; ++j) {
                const int R = wn + j * 16 + lrow;
                const int c = ((kk << 2) + g) ^ (R & 7);
                bf[j] = *(const s16x8*)&Bs[(R << 6) + (c << 3)];
            }
#pragma unroll
            for (int i = 0; i < 4; ++i)
#pragma unroll
                for (int j = 0; j < 4; ++j)
                    acc[i][j] = __builtin_amdgcn_mfma_f32_16x16x32_bf16(af[i], bf[j], acc[i][j], 0, 0, 0);
        }
        __syncthreads();
    }

    // ---- LDS-staged epilogue ----
    float* Es = (float*)Sm + wave * (16 * EST);

    const int wbase = n0 + wn;
    ushort* Cw; int ldw, cb;
    if (mode == 0) { Cw = C1; ldw = ld1; cb = wbase; }
    else if (mode == 1) {
        if (wbase < 512) { Cw = C1; ldw = ld1; cb = wbase; }
        else             { Cw = C2b; ldw = 1024; cb = wbase - 512; }
    } else {
        if (wbase < 128) { Cw = C1; ldw = 128; cb = wbase; }
        else             { Cw = C2b; ldw = 384; cb = wbase - 128; }
    }

    float bj[4];
#pragma unroll
    for (int j = 0; j < 4; ++j) bj[j] = bias[wbase + j * 16 + lrow];

    const int rbase = (lane >> 4) * 4;
    const int rrow  = lane >> 2;
    const int rcol  = (lane & 3) << 4;

#pragma unroll
    for (int i = 0; i < 4; ++i) {
#pragma unroll
        for (int j = 0; j < 4; ++j)
#pragma unroll
            for (int r = 0; r < 4; ++r) {
                float v = acc[i][j][r] + bj[j];
                if (relu) v = fmaxf(v, 0.f);
                Es[(rbase + r) * EST + j * 16 + lrow] = v;
            }
        const int gm = m0 + wm + i * 16 + rrow;
        if (gm < M) {
            const float* src = Es + rrow * EST + rcol;
            f32x4 f0 = *(const f32x4*)(src + 0);
            f32x4 f1 = *(const f32x4*)(src + 4);
            f32x4 f2 = *(const f32x4*)(src + 8);
            f32x4 f3 = *(const f32x4*)(src + 12);
            u32x4 o0, o1;
            o0[0] = f2b_pk(f0[0], f0[1]); o0[1] = f2b_pk(f0[2], f0[3]);
            o0[2] = f2b_pk(f1[0], f1[1]); o0[3] = f2b_pk(f1[2], f1[3]);
            o1[0] = f2b_pk(f2[0], f2[1]); o1[1] = f2b_pk(f2[2], f2[3]);
            o1[2] = f2b_pk(f3[0], f3[1]); o1[3] = f2b_pk(f3[2], f3[3]);
            ushort* dst = Cw + (size_t)gm * ldw + cb + rcol;
            *(u32x4*)(dst + 0) = o0;
            *(u32x4*)(dst + 8) = o1;
        }
    }
}

// ================= weight prep =================
// wt layout (rows [n][k], bf16):
//  [0, 8192)            Wpt   [128][64]
//  [8192, 204800)       F1    [1536][128] = Ws1t(512) | u-rows: M heads 0-3 (4x128, mcomp)
//                                          | v-rows: Wv1t heads 0-3 (4x128)
//  [204800, 466944)     F2    [512][512]  = Ws2t(128) | q2|k2|v2 (384)
// bb: [0,512) bs1; [512,1024) r_h (mcomp); [1024,1536) bv1; [1536,2048) F2
#define F1OFF  8192
#define F2OFF  204800
#define WTOTAL 466944
#define BTOT   2048

__global__ void wprep_kernel(
    const float* __restrict__ Wp,
    const float* __restrict__ Wq1, const float* __restrict__ Wk1,
    const float* __restrict__ Wv1, const float* __restrict__ Ws1,
    const float* __restrict__ Wq2, const float* __restrict__ Wk2,
    const float* __restrict__ Wv2, const float* __restrict__ Ws2,
    const float* __restrict__ bs1, const float* __restrict__ bv1,
    const float* __restrict__ bs2,
    const float* __restrict__ bq2, const float* __restrict__ bk2, const float* __restrict__ bv2,
    ushort* __restrict__ wt, float* __restrict__ bb)
{
    int t = blockIdx.x * 256 + threadIdx.x;
    if (t < WTOTAL) {
        float v;
        if (t < F1OFF) {
            int n = t >> 6, k = t & 63;
            v = Wp[k * 128 + n];
        } else if (t < F2OFF) {
            int u = t - F1OFF;
            int n = u >> 7, k = u & 127;
            if (n < 512) v = Ws1[k * 512 + n];
            else if (n < 1024) return;           // u (M) rows: filled by mcomp_kernel
            else {
                int r = n - 1024;                // 0..511 = h*128 + c
                v = Wv1[k * 512 + r];
            }
        } else {
            int u = t - F2OFF;
            int n = u >> 9, k = u & 511;
            if (n < 128) v = Ws2[k * 128 + n];
            else {
                int r = n - 128;
                const float* W = (r < 128) ? Wq2 : (r < 256) ? Wk2 : Wv2;
                v = W[k * 128 + (r & 127)];
            }
        }
        wt[t] = f2b(v);
    } else if (t < WTOTAL + BTOT) {
        int u = t - WTOTAL;
        float v;
        if (u < 512) v = bs1[u];
        else if (u < 1024) return;               // r_h bias: filled by mcomp_kernel
        else if (u < 1536) v = bv1[u - 1024];
        else {
            int c = u - 1536;
            v = (c < 128) ? bs2[c]
              : (c < 256) ? bq2[c - 128]
              : (c < 384) ? bk2[c - 256] : bv2[c - 384];
        }
        bb[u] = v;
    }
}

// ================= mcomp: per-head M = Wq Wk^T (bf16) and r = Wk bq (fp32 bias) ====
__global__ void mcomp_kernel(
    const float* __restrict__ Wq1, const float* __restrict__ Wk1,
    const float* __restrict__ bq1, ushort* __restrict__ wt, float* __restrict__ bb)
{
    int t = blockIdx.x * 256 + threadIdx.x;
    if (t < HEADS * 128 * 128) {
        int h = t >> 14;
        int rem = t & 16383;
        int b = rem >> 7, a = rem & 127;
        const float* wq = Wq1 + a * 512 + h * 128;
        const float* wk = Wk1 + b * 512 + h * 128;
        float acc = 0.f;
#pragma unroll 8
        for (int d = 0; d < 128; ++d) acc += wq[d] * wk[d];
        wt[F1OFF + (size_t)(512 + h * 128 + b) * 128 + a] = f2b(acc);
    } else if (t < HEADS * 128 * 128 + HEADS * 128) {
        int u = t - HEADS * 128 * 128;
        int h = u >> 7, b = u & 127;
        const float* wk = Wk1 + b * 512 + h * 128;
        const float* bq = bq1 + h * 128;
        float acc = 0.f;
#pragma unroll 8
        for (int d = 0; d < 128; ++d) acc += wk[d] * bq[d];
        bb[512 + h * 128 + b] = acc;
    }
}

// ================= fp32 -> bf16 (x4, packed cvt) =================
__global__ void f32_to_bf16_kernel(const float4* __restrict__ in, uint2* __restrict__ out, int n4)
{
    int i = blockIdx.x * 256 + threadIdx.x;
    if (i >= n4) return;
    float4 v = in[i];
    uint2 o;
    o.x = f2b_pk(v.x, v.y);
    o.y = f2b_pk(v.z, v.w);
    out[i] = o;
}

__global__ void fill_kernel(unsigned* __restrict__ p, unsigned v, int n) {
    int i = blockIdx.x * blockDim.x + threadIdx.x;
    if (i < n) p[i] = v;
}

// ================= CSR build (dst -> src list) — r14-proven 3-dispatch scan =================
__global__ void hist_kernel(const int* __restrict__ dst, int* __restrict__ cnt, int E) {
    int e = blockIdx.x * 256 + threadIdx.x;
    if (e < E) atomicAdd(&cnt[dst[e]], 1);
}

#define SCAN_B 1024
__global__ void scan_bsum_kernel(const int* __restrict__ cnt, int* __restrict__ bsum, int n) {
    __shared__ int sd[256];
    int tid = threadIdx.x;
    int base = blockIdx.x * SCAN_B + tid * 4;
    int s = 0;
#pragma unroll
    for (int j = 0; j < 4; ++j) if (base + j < n) s += cnt[base + j];
    sd[tid] = s;
    __syncthreads();
    for (int off = 128; off > 0; off >>= 1) {
        if (tid < off) sd[tid] += sd[tid + off];
        __syncthreads();
    }
    if (tid == 0) bsum[blockIdx.x] = sd[0];
}

__global__ void scan_excl_kernel(int* __restrict__ bsum, int nb) {
    if (threadIdx.x == 0 && blockIdx.x == 0) {
        int acc = 0;
        for (int i = 0; i < nb; ++i) { int v = bsum[i]; bsum[i] = acc; acc += v; }
    }
}

__global__ void scan_final_kernel(const int* __restrict__ cnt, const int* __restrict__ bsum,
                                  int* __restrict__ rowptr, int* __restrict__ cursor, int n) {
    __shared__ int sd[256];
    int tid = threadIdx.x;
    int base = blockIdx.x * SCAN_B + tid * 4;
    int v[4]; int s = 0;
#pragma unroll
    for (int j = 0; j < 4; ++j) { v[j] = (base + j < n) ? cnt[base + j] : 0; s += v[j]; }
    sd[tid] = s;
    __syncthreads();
    for (int off = 1; off < 256; off <<= 1) {
        int t2 = (tid >= off) ? sd[tid - off] : 0;
        __syncthreads();
        sd[tid] += t2;
        __syncthreads();
    }
    int acc = bsum[blockIdx.x] + sd[tid] - s;
#pragma unroll
    for (int j = 0; j < 4; ++j) {
        if (base + j < n) cursor[base + j] = acc;
        acc += v[j];
        if (base + j < n) rowptr[base + j + 1] = acc;
    }
    if (blockIdx.x == 0 && tid == 0) rowptr[0] = 0;
}

__global__ void bucket_kernel(const int* __restrict__ src, const int* __restrict__ dst,
                              int* __restrict__ cursor, int* __restrict__ srcs, int E) {
    int e = blockIdx.x * 256 + threadIdx.x;
    if (e >= E) return;
    int p = atomicAdd(&cursor[dst[e]], 1);
    srcs[p] = src[e];
}

// ================= conv1 gather: ALL 4 HEADS per wave (one wave per node) =================
// UV rows (1024 bf16): [u0|u1|u2|u3|v0|v1|v2|v3]. Kb = h0 rows (128 bf16).
// io: h1b rows (512 bf16) — skip in, result out, in place. relu fused.
__global__ __launch_bounds__(256) void gather4_kernel(
    const ushort* __restrict__ UV, const ushort* __restrict__ Kb,
    const int* __restrict__ rowptr, const int* __restrict__ srcs,
    ushort* __restrict__ io, float scale, int n)
{
    int i = blockIdx.x * 4 + (threadIdx.x >> 6);
    int lane = threadIdx.x & 63;
    if (i >= n) return;
    const uint* Qu = (const uint*)UV;        // row stride 512 uints
    const uint* Ku = (const uint*)Kb;        // row stride 64 uints

    float q0[4], q1[4];
#pragma unroll
    for (int h = 0; h < 4; ++h) {
        uint qv = Qu[(size_t)i * 512 + h * 64 + lane];
        q0[h] = b2f((ushort)qv); q1[h] = b2f((ushort)(qv >> 16));
    }
    int p0 = rowptr[i], p1 = rowptr[i + 1];
    float den[4] = {0.f, 0.f, 0.f, 0.f};
    float o0[4] = {0.f, 0.f, 0.f, 0.f};
    float o1[4] = {0.f, 0.f, 0.f, 0.f};
    int sn = (p0 < p1) ? srcs[p0] : 0;
    for (int p = p0; p < p1; ++p) {
        int s = sn;
        sn = (p + 1 < p1) ? srcs[p + 1] : 0;              // prefetch next src index
        uint kv = Ku[(size_t)s * 64 + lane];
        uint vv[4];
#pragma unroll
        for (int h = 0; h < 4; ++h)
            vv[h] = Qu[(size_t)s * 512 + 256 + h * 64 + lane];
        float k0 = b2f((ushort)kv), k1 = b2f((ushort)(kv >> 16));
        float d[4];
#pragma unroll
        for (int h = 0; h < 4; ++h) d[h] = q0[h] * k0 + q1[h] * k1;
#pragma unroll
        for (int off = 32; off > 0; off >>= 1) {
#pragma unroll
            for (int h = 0; h < 4; ++h) d[h] += __shfl_xor(d[h], off, 64);
        }
#pragma unroll
        for (int h = 0; h < 4; ++h) {
            float e = __expf(d[h] * scale);
            den[h] += e;
            o0[h] += e * b2f((ushort)vv[h]);
            o1[h] += e * b2f((ushort)(vv[h] >> 16));
        }
    }
#pragma unroll
    for (int h = 0; h < 4; ++h) {
        uint sk = ((const uint*)io)[(size_t)i * 256 + h * 64 + lane];
        float inv = 1.0f / (den[h] + 1e-16f);
        float r0 = fmaxf(b2f((ushort)sk) + o0[h] * inv, 0.f);
        float r1 = fmaxf(b2f((ushort)(sk >> 16)) + o1[h] * inv, 0.f);
        ((uint*)io)[(size_t)i * 256 + h * 64 + lane] = f2b_pk(r0, r1);
    }
}

// ================= conv2 gather (single head, q|k|v rows ld=384, ILP-2) =================
__global__ __launch_bounds__(256) void edge_gather_kernel(
    const ushort* __restrict__ qkv,
    const int* __restrict__ rowptr, const int* __restrict__ srcs,
    const ushort* __restrict__ skip,
    ushort* __restrict__ outp, float scale, int n)
{
    int i = blockIdx.x * 4 + (threadIdx.x >> 6);
    int lane = threadIdx.x & 63;
    if (i >= n) return;
    const uint* Qu = (const uint*)qkv;       // row stride 192 uints

    uint sk = ((const uint*)skip)[(size_t)i * 64 + lane];
    uint qv = Qu[(size_t)i * 192 + lane];
    float q0 = b2f((ushort)qv), q1 = b2f((ushort)(qv >> 16));
    int p0 = rowptr[i], p1 = rowptr[i + 1];
    float den = 0.f, o0 = 0.f, o1 = 0.f;
    int p = p0;
    for (; p + 2 <= p1; p += 2) {
        int s0 = srcs[p], s1 = srcs[p + 1];
        const uint* kr0 = Qu + (size_t)s0 * 192 + 64;
        const uint* kr1 = Qu + (size_t)s1 * 192 + 64;
        uint kv0 = kr0[lane], vv0 = kr0[lane + 64];
        uint kv1 = kr1[lane], vv1 = kr1[lane + 64];
        float d0 = q0 * b2f((ushort)kv0) + q1 * b2f((ushort)(kv0 >> 16));
        float d1 = q0 * b2f((ushort)kv1) + q1 * b2f((ushort)(kv1 >> 16));
#pragma unroll
        for (int off = 32; off > 0; off >>= 1) {
            d0 += __shfl_xor(d0, off, 64);
            d1 += __shfl_xor(d1, off, 64);
        }
        float e0 = __expf(d0 * scale), e1 = __expf(d1 * scale);
        den += e0 + e1;
        o0 += e0 * b2f((ushort)vv0) + e1 * b2f((ushort)vv1);
        o1 += e0 * b2f((ushort)(vv0 >> 16)) + e1 * b2f((ushort)(vv1 >> 16));
    }
    if (p < p1) {
        int s = srcs[p];
        const uint* kr = Qu + (size_t)s * 192 + 64;
        uint kv = kr[lane], vv = kr[lane + 64];
        float d = q0 * b2f((ushort)kv) + q1 * b2f((ushort)(kv >> 16));
#pragma unroll
        for (int off = 32; off > 0; off >>= 1) d += __shfl_xor(d, off, 64);
        float e = __expf(d * scale);
        den += e;
        o0 += e * b2f((ushort)vv);
        o1 += e * b2f((ushort)(vv >> 16));
    }
    float inv = 1.0f / (den + 1e-16f);
    float r0 = b2f((ushort)sk) + o0 * inv;
    float r1 = b2f((ushort)(sk >> 16)) + o1 * inv;
    ((uint*)outp)[(size_t)i * 64 + lane] = f2b_pk(r0, r1);
}

// ================= pool over bf16 h2: run-length partial sums (+fused relu) =================
__global__ __launch_bounds__(256) void pool_kernel(
    const ushort* __restrict__ h, const int* __restrict__ batch,
    float* __restrict__ gsum, float* __restrict__ cnt, int n)
{
    int wave = threadIdx.x >> 6, lane = threadIdx.x & 63;
    int start = blockIdx.x * 256 + wave * 64;
    int end = min(start + 64, n);
    if (start >= end) return;
    int cur = batch[start];
    float a0 = 0.f, a1 = 0.f;
    int run = 0;
    for (int node = start; node < end; ++node) {
        int g = batch[node];
        if (g != cur) {
            atomicAdd(&gsum[cur * HH + 2 * lane], a0);
            atomicAdd(&gsum[cur * HH + 2 * lane + 1], a1);
            if (lane == 0) atomicAdd(&cnt[cur], (float)run);
            cur = g; a0 = a1 = 0.f; run = 0;
        }
        uint x = ((const uint*)h)[(size_t)node * 64 + lane];
        a0 += fmaxf(b2f((ushort)x), 0.f);
        a1 += fmaxf(b2f((ushort)(x >> 16)), 0.f);
        ++run;
    }
    atomicAdd(&gsum[cur * HH + 2 * lane], a0);
    atomicAdd(&gsum[cur * HH + 2 * lane + 1], a1);
    if (lane == 0) atomicAdd(&cnt[cur], (float)run);
}

__global__ void pool_fin_kernel(const float* __restrict__ gsum,
                                const float* __restrict__ cnt, float* __restrict__ g)
{
    int i = blockIdx.x * blockDim.x + threadIdx.x;
    if (i < BB * HH) g[i] = gsum[i] / fmaxf(cnt[i / HH], 1.0f);
}

// ================= output heads =================
__global__ void out_heads_kernel(
    const float* __restrict__ g,
    const float* __restrict__ w0, const float* __restrict__ b0,
    const float* __restrict__ w1, const float* __restrict__ b1,
    const float* __restrict__ w2, const float* __restrict__ b2,
    const float* __restrict__ w3, const float* __restrict__ b3,
    const float* __restrict__ w4, const float* __restrict__ b4,
    const float* __restrict__ w5, const float* __restrict__ b5,
    const float* __restrict__ w6, const float* __restrict__ b6,
    float* __restrict__ out, int total)
{
    int t = blockIdx.x * blockDim.x + threadIdx.x;
    if (t >= total) return;
    const float* W; const float* bias; int cols; int local;
    if      (t < 64)    { W = w0; bias = b0; cols = 1;   local = t; }
    else if (t < 320)   { W = w1; bias = b1; cols = 4;   local = t - 64; }
    else if (t < 512)   { W = w2; bias = b2; cols = 3;   local = t - 320; }
    else if (t < 33280) { W = w3; bias = b3; cols = SS;  local = t - 512; }
    else if (t < 66048) { W = w4; bias = b4; cols = SS;  local = t - 33280; }
    else if (t < 98816) { W = w5; bias = b5; cols = SS;  local = t - 66048; }
    else                { W = w6; bias = b6; cols = LCC; local = t - 98816; }
    int b = local / cols, c = local % cols;
    const float* gr = g + b * HH;
    float acc = bias[c];
#pragma unroll 8
    for (int i = 0; i < HH; ++i) acc += gr[i] * W[i * cols + c];
    out[t] = acc;
}

// ================= orchestration =================
extern "C" void kernel_launch(void* const* d_in, const int* in_sizes, int n_in,
                              void* d_out, int out_size, void* d_ws, size_t ws_size,
                              hipStream_t stream)
{
    (void)in_sizes; (void)n_in; (void)out_size; (void)ws_size;

    const float* nf   = (const float*)d_in[0];
    const int*   ei   = (const int*)d_in[1];
    const int*   src  = ei;
    const int*   dst  = ei + EE;
    const int*   batch= (const int*)d_in[2];
    const float* Wp   = (const float*)d_in[3];
    const float* bp   = (const float*)d_in[4];
    const float* Wq1  = (const float*)d_in[5];
    const float* bq1  = (const float*)d_in[6];
    const float* Wk1  = (const float*)d_in[7];
    const float* bk1  = (const float*)d_in[8];
    const float* Wv1  = (const float*)d_in[9];
    const float* bv1  = (const float*)d_in[10];
    const float* Ws1  = (const float*)d_in[11];
    const float* bs1  = (const float*)d_in[12];
    const float* Wq2  = (const float*)d_in[13];
    const float* bq2  = (const float*)d_in[14];
    const float* Wk2  = (const float*)d_in[15];
    const float* bk2  = (const float*)d_in[16];
    const float* Wv2  = (const float*)d_in[17];
    const float* bv2  = (const float*)d_in[18];
    const float* Ws2  = (const float*)d_in[19];
    const float* bs2  = (const float*)d_in[20];
    const float* crW  = (const float*)d_in[21];
    const float* crb  = (const float*)d_in[22];
    const float* hlW  = (const float*)d_in[23];
    const float* hlb  = (const float*)d_in[24];
    const float* mtW  = (const float*)d_in[25];
    const float* mtb  = (const float*)d_in[26];
    const float* p1W  = (const float*)d_in[27];
    const float* p1b  = (const float*)d_in[28];
    const float* p2W  = (const float*)d_in[29];
    const float* p2b  = (const float*)d_in[30];
    const float* dtW  = (const float*)d_in[31];
    const float* dtb  = (const float*)d_in[32];
    const float* slW  = (const float*)d_in[33];
    const float* slb  = (const float*)d_in[34];
    float* out = (float*)d_out;

    (void)bk1;   // bk1 contributes only a per-dst-constant score shift (cancels in softmax)

    // ---- workspace layout (~167 MB; r14/r16-proven footprint) ----
    ushort* UV     = (ushort*)d_ws;                        // N*1024 rows [u0..u3|v0..v3]
    ushort* nfb    = UV;
    ushort* h2sb   = UV;                                   // N*128 (conv2 phase aliases)
    ushort* qkvO   = UV + (size_t)NN * 256;                // N*384
    ushort* h2     = UV + (size_t)NN * 640;                // N*128
    ushort* h0b    = UV + (size_t)NN * 1024;               // N*128
    ushort* h1b    = h0b + (size_t)NN * 128;               // N*512 (conv1 skip AND out, in-place)
    ushort* wt     = h1b + (size_t)NN * 512;               // prepped weights
    float*  bb     = (float*)(wt + WTOTAL);                // fused biases
    int*    rowptr = (int*)(bb + BTOT);                    // N+1
    int*    srcs   = rowptr + NN + 1;                      // E
    int*    cnt    = srcs + EE;                            // N   (zeroed together with gsum/cntb)
    float*  gsum   = (float*)(cnt + NN);                   // B*128
    float*  cntb   = gsum + BB * HH;                       // B
    int*    cursor = (int*)(cntb + BB);                    // N
    int*    bsum   = cursor + NN;                          // 64
    float*  gbuf   = (float*)(bsum + 64);                  // B*128

    const float scale = 0.08838834764831845f; // 1/sqrt(128)
    const dim3 blk(256);
    const int gy  = (NN + BM - 1) / BM;         // 391 row-blocks
    const int gyp = ((gy + 7) / 8) * 8;         // 392 (XCD-padded)
    const int nb = (NN + SCAN_B - 1) / SCAN_B;  // 49

    // 1) weight prep + bilinear M/r composition
    wprep_kernel<<<(WTOTAL + BTOT + 255) / 256, blk, 0, stream>>>(
        Wp, Wq1, Wk1, Wv1, Ws1, Wq2, Wk2, Wv2, Ws2,
        bs1, bv1, bs2, bq2, bk2, bv2, wt, bb);
    mcomp_kernel<<<(HEADS * 128 * 128 + HEADS * 128 + 255) / 256, blk, 0, stream>>>(
        Wq1, Wk1, bq1, wt, bb);

    // 2) nf -> bf16
    f32_to_bf16_kernel<<<((NN * FF / 4) + 255) / 256, blk, 0, stream>>>(
        (const float4*)nf, (uint2*)nfb, NN * FF / 4);

    // 3) CSR build (r14-proven parallel 3-dispatch scan)
    fill_kernel<<<(NN + BB * HH + BB + 255) / 256, blk, 0, stream>>>(
        (unsigned*)cnt, 0u, NN + BB * HH + BB);
    hist_kernel<<<(EE + 255) / 256, blk, 0, stream>>>(dst, cnt, EE);
    scan_bsum_kernel<<<nb, blk, 0, stream>>>(cnt, bsum, NN);
    scan_excl_kernel<<<1, 64, 0, stream>>>(bsum, nb);
    scan_final_kernel<<<nb, blk, 0, stream>>>(cnt, bsum, rowptr, cursor, NN);
    bucket_kernel<<<(EE + 255) / 256, blk, 0, stream>>>(src, dst, cursor, srcs, EE);

    // 4) proj: h0b = relu(nf @ Wp + bp)   (mode 0, gx=1, K=64)
    gemm_bf16<<<dim3(1 * gyp), blk, 0, stream>>>(
        nfb, wt, bp, h0b, HH, h0b, 0, NN, FF, 1, 1, gy);

    // 5) F1-mega: [skip(512)->h1b | u0..3|v0..3 -> UV rows]   (mode 1, gx=12, K=128)
    gemm_bf16<<<dim3(12 * gyp), blk, 0, stream>>>(
        h0b, wt + F1OFF, bb, h1b, 512, UV, 1, NN, HH, 0, 12, gy);

    // 6) fused 4-head gather (one wave per node; k = h0, shared)
    gather4_kernel<<<(NN + 3) / 4, blk, 0, stream>>>(
        UV, h0b, rowptr, srcs, h1b, scale, NN);

    // 7) F2: [skip(128)->h2sb | qkv(384)->qkvO]   (mode 2, gx=4, K=512)
    gemm_bf16<<<dim3(4 * gyp), blk, 0, stream>>>(
        h1b, wt + F2OFF, bb + 1536, h2sb, 128, qkvO, 2, NN, 4 * HH, 0, 4, gy);

    // 8) gather conv2 (single head)
    edge_gather_kernel<<<(NN + 3) / 4, blk, 0, stream>>>(
        qkvO, rowptr, srcs, h2sb, h2, scale, NN);

    // 9) pool (relu fused, bf16 input) + finalize
    pool_kernel<<<(NN + 255) / 256, blk, 0, stream>>>(h2, batch, gsum, cntb, NN);
    pool_fin_kernel<<<(BB * HH + 255) / 256, blk, 0, stream>>>(gsum, cntb, gbuf);

    // 10) output heads
    const int total = BB * (1 + 4 + 3 + SS + SS + SS + LCC);
    out_heads_kernel<<<(total + 255) / 256, blk, 0, stream>>>(
        gbuf, crW, crb, hlW, hlb, mtW, mtb, p1W, p1b, p2W, p2b, dtW, dtb, slW, slb, out, total);
}

// Round 18
// 369.893 us; speedup vs baseline: 1.2999x; 1.0111x over previous
//
#include <hip/hip_runtime.h>
#include <hip/hip_bf16.h>

#define NN 50000
#define EE 100000
#define FF 64
#define HH 128
#define HEADS 4
#define BB 64
#define SS 512
#define LCC 8

// ---- bf16 helpers ----
__device__ __forceinline__ float b2f(ushort u) {
    return __uint_as_float(((unsigned)u) << 16);
}
__device__ __forceinline__ ushort f2b(float f) {
    unsigned u = __float_as_uint(f);
    unsigned r = (u + 0x7FFFu + ((u >> 16) & 1u)) >> 16;   // RNE
    return (ushort)r;
}
// packed RNE convert: 2 f32 -> 1 uint (low = a), maps to v_cvt_pk_bf16_f32
__device__ __forceinline__ uint f2b_pk(float a, float b) {
    __hip_bfloat162 h = __float22bfloat162_rn(make_float2(a, b));
    return *reinterpret_cast<uint*>(&h);
}

typedef __attribute__((ext_vector_type(4))) float f32x4;
typedef __attribute__((ext_vector_type(8))) short s16x8;
typedef __attribute__((ext_vector_type(4))) uint u32x4;

__device__ __forceinline__ void glls16(const ushort* g, ushort* l) {
    __builtin_amdgcn_global_load_lds((const __attribute__((address_space(1))) void*)g,
                                     (__attribute__((address_space(3))) void*)l, 16, 0, 0);
}

// ================= bf16 MFMA GEMM (r12-proven core + packed-cvt epilogue) =================
// C = A[M,K] @ Bt[N,K]^T + bias, bf16 out. Destination select by mode (wave-uniform):
//  mode 0: all cols -> C1 (ld1)
//  mode 1: cols<512 -> C1 (ld1); else head h=(col-512)/256 -> C2b + h*NN*256, ld 256 (r16 layout)
//  mode 2: cols<128 -> C1 (ld 128); else -> C2b (ld 384), col-128
#define BM 128
#define BN 128
#define BK 64
#define EST 68   // epilogue staging stride (f32) — breaks power-of-2 bank aliasing

__global__ __launch_bounds__(256) void gemm_bf16(
    const ushort* __restrict__ A, const ushort* __restrict__ Bt,
    const float* __restrict__ bias,
    ushort* __restrict__ C1, int ld1,
    ushort* __restrict__ C2b, int mode,
    int M, int K, int relu, int gx, int gy)
{
    __shared__ __align__(16) ushort Sm[2 * BM * BK];   // 32 KB: As | Bs, reused by epilogue
    ushort* As = Sm;
    ushort* Bs = Sm + BM * BK;

    const int bid  = blockIdx.x;
    const int xcd  = bid & 7;
    const int slot = bid >> 3;
    const int bx   = slot % gx;
    const int by   = xcd + 8 * (slot / gx);
    if (by >= gy) return;
    const int m0 = by * BM;
    const int n0 = bx * BN;

    const int t = threadIdx.x;
    const int lane = t & 63;
    const int wave = t >> 6;
    const int wm = (wave & 1) * 64;
    const int wn = (wave >> 1) * 64;
    const int lrow = lane & 15;
    const int g    = lane >> 4;

    const int srow = (wave << 5) + (lane >> 3);
    const int scs  = lane & 7;

    const ushort* ga[4];
    const ushort* gb[4];
#pragma unroll
    for (int p = 0; p < 4; ++p) {
        const int row = srow + (p << 3);
        const int l   = scs ^ (row & 7);
        ga[p] = A + (size_t)min(m0 + row, M - 1) * K + (l << 3);
        gb[p] = Bt + (size_t)(n0 + row) * K + (l << 3);
    }
    const int ldsoff = (wave << 11);

    f32x4 acc[4][4] = {};

    for (int k0 = 0; k0 < K; k0 += BK) {
#pragma unroll
        for (int p = 0; p < 4; ++p) glls16(ga[p] + k0, As + ldsoff + (p << 9));
#pragma unroll
        for (int p = 0; p < 4; ++p) glls16(gb[p] + k0, Bs + ldsoff + (p << 9));
        __syncthreads();

#pragma unroll
        for (int kk = 0; kk < 2; ++kk) {
            s16x8 af[4], bf[4];
#pragma unroll
            for (int i = 0; i < 4; ++i) {
                const int R = wm + i * 16 + lrow;
                const int c = ((kk << 2) + g) ^ (R & 7);
                af[i] = *(const s16x8*)&As[(R << 6) + (c << 3)];
            }
#pragma unroll
            for (int j = 0; j < 4; ++j) {
                const int R = wn + j * 16 + lrow;
                const int c = ((kk << 2) + g) ^ (R & 7);
                bf[j] = *(const s16x8*)&Bs[(R << 6) + (c << 3)];
            }
#pragma unroll
            for (int i = 0; i < 4; ++i)
#pragma unroll
                for (int j = 0; j < 4; ++j)
                    acc[i][j] = __builtin_amdgcn_mfma_f32_16x16x32_bf16(af[i], bf[j], acc[i][j], 0, 0, 0);
        }
        __syncthreads();
    }

    // ---- LDS-staged epilogue (packed cvt) ----
    float* Es = (float*)Sm + wave * (16 * EST);

    const int wbase = n0 + wn;
    ushort* Cw; int ldw, cb;
    if (mode == 0) { Cw = C1; ldw = ld1; cb = wbase; }
    else if (mode == 1) {
        if (wbase < 512) { Cw = C1; ldw = ld1; cb = wbase; }
        else {
            const int u = wbase - 512;
            const int h = u >> 8;                // 256 cols per head: u(128) | v(128)
            cb = u & 255;
            Cw = C2b + (size_t)h * NN * 256; ldw = 256;
        }
    } else {
        if (wbase < 128) { Cw = C1; ldw = 128; cb = wbase; }
        else             { Cw = C2b; ldw = 384; cb = wbase - 128; }
    }

    float bj[4];
#pragma unroll
    for (int j = 0; j < 4; ++j) bj[j] = bias[wbase + j * 16 + lrow];

    const int rbase = (lane >> 4) * 4;
    const int rrow  = lane >> 2;
    const int rcol  = (lane & 3) << 4;

#pragma unroll
    for (int i = 0; i < 4; ++i) {
#pragma unroll
        for (int j = 0; j < 4; ++j)
#pragma unroll
            for (int r = 0; r < 4; ++r) {
                float v = acc[i][j][r] + bj[j];
                if (relu) v = fmaxf(v, 0.f);
                Es[(rbase + r) * EST + j * 16 + lrow] = v;
            }
        const int gm = m0 + wm + i * 16 + rrow;
        if (gm < M) {
            const float* src = Es + rrow * EST + rcol;
            f32x4 f0 = *(const f32x4*)(src + 0);
            f32x4 f1 = *(const f32x4*)(src + 4);
            f32x4 f2 = *(const f32x4*)(src + 8);
            f32x4 f3 = *(const f32x4*)(src + 12);
            u32x4 o0, o1;
            o0[0] = f2b_pk(f0[0], f0[1]); o0[1] = f2b_pk(f0[2], f0[3]);
            o0[2] = f2b_pk(f1[0], f1[1]); o0[3] = f2b_pk(f1[2], f1[3]);
            o1[0] = f2b_pk(f2[0], f2[1]); o1[1] = f2b_pk(f2[2], f2[3]);
            o1[2] = f2b_pk(f3[0], f3[1]); o1[3] = f2b_pk(f3[2], f3[3]);
            ushort* dst = Cw + (size_t)gm * ldw + cb + rcol;
            *(u32x4*)(dst + 0) = o0;
            *(u32x4*)(dst + 8) = o1;
        }
    }
}

// ================= weight prep (r16 per-head u|v layout) =================
// wt layout (rows [n][k], bf16):
//  [0, 8192)            Wpt   [128][64]
//  [8192, 204800)       F1    [1536][128] = Ws1t(512) | per head: u(128, mcomp) | v(128)
//  [204800, 466944)     F2    [512][512]  = Ws2t(128) | q2|k2|v2 (384)
// bb: [0,512) bs1; per head [512+h*256,+128) r_h (mcomp), [+128,+256) bv1; [1536,2048) F2
#define F1OFF  8192
#define F2OFF  204800
#define WTOTAL 466944
#define BTOT   2048

__global__ void wprep_kernel(
    const float* __restrict__ Wp,
    const float* __restrict__ Wq1, const float* __restrict__ Wk1,
    const float* __restrict__ Wv1, const float* __restrict__ Ws1,
    const float* __restrict__ Wq2, const float* __restrict__ Wk2,
    const float* __restrict__ Wv2, const float* __restrict__ Ws2,
    const float* __restrict__ bs1, const float* __restrict__ bv1,
    const float* __restrict__ bs2,
    const float* __restrict__ bq2, const float* __restrict__ bk2, const float* __restrict__ bv2,
    ushort* __restrict__ wt, float* __restrict__ bb)
{
    int t = blockIdx.x * 256 + threadIdx.x;
    if (t < WTOTAL) {
        float v;
        if (t < F1OFF) {
            int n = t >> 6, k = t & 63;
            v = Wp[k * 128 + n];
        } else if (t < F2OFF) {
            int u = t - F1OFF;
            int n = u >> 7, k = u & 127;
            if (n < 512) v = Ws1[k * 512 + n];
            else {
                int r = n - 512;
                int h = r >> 8, c = r & 255;
                if (c < 128) return;             // u (M) rows: filled by mcomp_kernel
                v = Wv1[k * 512 + h * 128 + (c - 128)];
            }
        } else {
            int u = t - F2OFF;
            int n = u >> 9, k = u & 511;
            if (n < 128) v = Ws2[k * 128 + n];
            else {
                int r = n - 128;
                const float* W = (r < 128) ? Wq2 : (r < 256) ? Wk2 : Wv2;
                v = W[k * 128 + (r & 127)];
            }
        }
        wt[t] = f2b(v);
    } else if (t < WTOTAL + BTOT) {
        int u = t - WTOTAL;
        float v;
        if (u < 512) v = bs1[u];
        else if (u < 1536) {
            int r = u - 512;
            int h = r >> 8, c = r & 255;
            if (c < 128) return;                 // r_h bias: filled by mcomp_kernel
            v = bv1[h * 128 + (c - 128)];
        } else {
            int c = u - 1536;
            v = (c < 128) ? bs2[c]
              : (c < 256) ? bq2[c - 128]
              : (c < 384) ? bk2[c - 256] : bv2[c - 384];
        }
        bb[u] = v;
    }
}

// ================= mcomp: per-head M = Wq Wk^T (bf16) and r = Wk bq (fp32 bias) ====
__global__ void mcomp_kernel(
    const float* __restrict__ Wq1, const float* __restrict__ Wk1,
    const float* __restrict__ bq1, ushort* __restrict__ wt, float* __restrict__ bb)
{
    int t = blockIdx.x * 256 + threadIdx.x;
    if (t < HEADS * 128 * 128) {
        int h = t >> 14;
        int rem = t & 16383;
        int b = rem >> 7, a = rem & 127;
        const float* wq = Wq1 + a * 512 + h * 128;
        const float* wk = Wk1 + b * 512 + h * 128;
        float acc = 0.f;
#pragma unroll 8
        for (int d = 0; d < 128; ++d) acc += wq[d] * wk[d];
        wt[F1OFF + (size_t)(512 + h * 256 + b) * 128 + a] = f2b(acc);
    } else if (t < HEADS * 128 * 128 + HEADS * 128) {
        int u = t - HEADS * 128 * 128;
        int h = u >> 7, b = u & 127;
        const float* wk = Wk1 + b * 512 + h * 128;
        const float* bq = bq1 + h * 128;
        float acc = 0.f;
#pragma unroll 8
        for (int d = 0; d < 128; ++d) acc += wk[d] * bq[d];
        bb[512 + h * 256 + b] = acc;
    }
}

// ================= fp32 -> bf16 (x4, packed cvt) =================
__global__ void f32_to_bf16_kernel(const float4* __restrict__ in, uint2* __restrict__ out, int n4)
{
    int i = blockIdx.x * 256 + threadIdx.x;
    if (i >= n4) return;
    float4 v = in[i];
    uint2 o;
    o.x = f2b_pk(v.x, v.y);
    o.y = f2b_pk(v.z, v.w);
    out[i] = o;
}

__global__ void fill_kernel(unsigned* __restrict__ p, unsigned v, int n) {
    int i = blockIdx.x * blockDim.x + threadIdx.x;
    if (i < n) p[i] = v;
}

// ================= CSR build (dst -> src list) — r14-proven 3-dispatch scan =================
__global__ void hist_kernel(const int* __restrict__ dst, int* __restrict__ cnt, int E) {
    int e = blockIdx.x * 256 + threadIdx.x;
    if (e < E) atomicAdd(&cnt[dst[e]], 1);
}

#define SCAN_B 1024
__global__ void scan_bsum_kernel(const int* __restrict__ cnt, int* __restrict__ bsum, int n) {
    __shared__ int sd[256];
    int tid = threadIdx.x;
    int base = blockIdx.x * SCAN_B + tid * 4;
    int s = 0;
#pragma unroll
    for (int j = 0; j < 4; ++j) if (base + j < n) s += cnt[base + j];
    sd[tid] = s;
    __syncthreads();
    for (int off = 128; off > 0; off >>= 1) {
        if (tid < off) sd[tid] += sd[tid + off];
        __syncthreads();
    }
    if (tid == 0) bsum[blockIdx.x] = sd[0];
}

__global__ void scan_excl_kernel(int* __restrict__ bsum, int nb) {
    if (threadIdx.x == 0 && blockIdx.x == 0) {
        int acc = 0;
        for (int i = 0; i < nb; ++i) { int v = bsum[i]; bsum[i] = acc; acc += v; }
    }
}

__global__ void scan_final_kernel(const int* __restrict__ cnt, const int* __restrict__ bsum,
                                  int* __restrict__ rowptr, int* __restrict__ cursor, int n) {
    __shared__ int sd[256];
    int tid = threadIdx.x;
    int base = blockIdx.x * SCAN_B + tid * 4;
    int v[4]; int s = 0;
#pragma unroll
    for (int j = 0; j < 4; ++j) { v[j] = (base + j < n) ? cnt[base + j] : 0; s += v[j]; }
    sd[tid] = s;
    __syncthreads();
    for (int off = 1; off < 256; off <<= 1) {
        int t2 = (tid >= off) ? sd[tid - off] : 0;
        __syncthreads();
        sd[tid] += t2;
        __syncthreads();
    }
    int acc = bsum[blockIdx.x] + sd[tid] - s;
#pragma unroll
    for (int j = 0; j < 4; ++j) {
        if (base + j < n) cursor[base + j] = acc;
        acc += v[j];
        if (base + j < n) rowptr[base + j + 1] = acc;
    }
    if (blockIdx.x == 0 && tid == 0) rowptr[0] = 0;
}

__global__ void bucket_kernel(const int* __restrict__ src, const int* __restrict__ dst,
                              int* __restrict__ cursor, int* __restrict__ srcs, int E) {
    int e = blockIdx.x * 256 + threadIdx.x;
    if (e >= E) return;
    int p = atomicAdd(&cursor[dst[e]], 1);
    srcs[p] = src[e];
}

// ================= conv1 gather: ALL 4 HEADS per wave (one wave per node) =================
// Qb: 4 head buffers (stride NN*256 us), row = [u(128)|v(128)]. Kb = h0 rows (128 bf16).
// io: h1b rows (512 bf16) — skip in, result out, in place. relu fused. Packed cvt stores.
__global__ __launch_bounds__(256) void gather4_kernel(
    const ushort* __restrict__ Qb, const ushort* __restrict__ Kb,
    const int* __restrict__ rowptr, const int* __restrict__ srcs,
    ushort* __restrict__ io, float scale, int n)
{
    int i = blockIdx.x * 4 + (threadIdx.x >> 6);
    int lane = threadIdx.x & 63;
    if (i >= n) return;
    const uint* Qu = (const uint*)Qb;        // row stride 128 uints per head-buffer
    const uint* Ku = (const uint*)Kb;        // row stride 64 uints

    float q0[4], q1[4];
#pragma unroll
    for (int h = 0; h < 4; ++h) {
        uint qv = Qu[((size_t)h * NN + i) * 128 + lane];
        q0[h] = b2f((ushort)qv); q1[h] = b2f((ushort)(qv >> 16));
    }
    int p0 = rowptr[i], p1 = rowptr[i + 1];
    float den[4] = {0.f, 0.f, 0.f, 0.f};
    float o0[4] = {0.f, 0.f, 0.f, 0.f};
    float o1[4] = {0.f, 0.f, 0.f, 0.f};
    int sn = (p0 < p1) ? srcs[p0] : 0;
    for (int p = p0; p < p1; ++p) {
        int s = sn;
        sn = (p + 1 < p1) ? srcs[p + 1] : 0;              // prefetch next src index
        uint kv = Ku[(size_t)s * 64 + lane];
        uint vv[4];
#pragma unroll
        for (int h = 0; h < 4; ++h)
            vv[h] = Qu[((size_t)h * NN + s) * 128 + 64 + lane];
        float k0 = b2f((ushort)kv), k1 = b2f((ushort)(kv >> 16));
        float d[4];
#pragma unroll
        for (int h = 0; h < 4; ++h) d[h] = q0[h] * k0 + q1[h] * k1;
#pragma unroll
        for (int off = 32; off > 0; off >>= 1) {
#pragma unroll
            for (int h = 0; h < 4; ++h) d[h] += __shfl_xor(d[h], off, 64);
        }
#pragma unroll
        for (int h = 0; h < 4; ++h) {
            float e = __expf(d[h] * scale);
            den[h] += e;
            o0[h] += e * b2f((ushort)vv[h]);
            o1[h] += e * b2f((ushort)(vv[h] >> 16));
        }
    }
#pragma unroll
    for (int h = 0; h < 4; ++h) {
        uint sk = ((const uint*)io)[(size_t)i * 256 + h * 64 + lane];
        float inv = 1.0f / (den[h] + 1e-16f);
        float r0 = fmaxf(b2f((ushort)sk) + o0[h] * inv, 0.f);
        float r1 = fmaxf(b2f((ushort)(sk >> 16)) + o1[h] * inv, 0.f);
        ((uint*)io)[(size_t)i * 256 + h * 64 + lane] = f2b_pk(r0, r1);
    }
}

// ================= conv2 gather (single head, q|k|v rows ld=384, ILP-2) =================
__global__ __launch_bounds__(256) void edge_gather_kernel(
    const ushort* __restrict__ qkv,
    const int* __restrict__ rowptr, const int* __restrict__ srcs,
    const ushort* __restrict__ skip,
    ushort* __restrict__ outp, float scale, int n)
{
    int i = blockIdx.x * 4 + (threadIdx.x >> 6);
    int lane = threadIdx.x & 63;
    if (i >= n) return;
    const uint* Qu = (const uint*)qkv;       // row stride 192 uints

    uint sk = ((const uint*)skip)[(size_t)i * 64 + lane];
    uint qv = Qu[(size_t)i * 192 + lane];
    float q0 = b2f((ushort)qv), q1 = b2f((ushort)(qv >> 16));
    int p0 = rowptr[i], p1 = rowptr[i + 1];
    float den = 0.f, o0 = 0.f, o1 = 0.f;
    int p = p0;
    for (; p + 2 <= p1; p += 2) {
        int s0 = srcs[p], s1 = srcs[p + 1];
        const uint* kr0 = Qu + (size_t)s0 * 192 + 64;
        const uint* kr1 = Qu + (size_t)s1 * 192 + 64;
        uint kv0 = kr0[lane], vv0 = kr0[lane + 64];
        uint kv1 = kr1[lane], vv1 = kr1[lane + 64];
        float d0 = q0 * b2f((ushort)kv0) + q1 * b2f((ushort)(kv0 >> 16));
        float d1 = q0 * b2f((ushort)kv1) + q1 * b2f((ushort)(kv1 >> 16));
#pragma unroll
        for (int off = 32; off > 0; off >>= 1) {
            d0 += __shfl_xor(d0, off, 64);
            d1 += __shfl_xor(d1, off, 64);
        }
        float e0 = __expf(d0 * scale), e1 = __expf(d1 * scale);
        den += e0 + e1;
        o0 += e0 * b2f((ushort)vv0) + e1 * b2f((ushort)vv1);
        o1 += e0 * b2f((ushort)(vv0 >> 16)) + e1 * b2f((ushort)(vv1 >> 16));
    }
    if (p < p1) {
        int s = srcs[p];
        const uint* kr = Qu + (size_t)s * 192 + 64;
        uint kv = kr[lane], vv = kr[lane + 64];
        float d = q0 * b2f((ushort)kv) + q1 * b2f((ushort)(kv >> 16));
#pragma unroll
        for (int off = 32; off > 0; off >>= 1) d += __shfl_xor(d, off, 64);
        float e = __expf(d * scale);
        den += e;
        o0 += e * b2f((ushort)vv);
        o1 += e * b2f((ushort)(vv >> 16));
    }
    float inv = 1.0f / (den + 1e-16f);
    float r0 = b2f((ushort)sk) + o0 * inv;
    float r1 = b2f((ushort)(sk >> 16)) + o1 * inv;
    ((uint*)outp)[(size_t)i * 64 + lane] = f2b_pk(r0, r1);
}

// ================= pool over bf16 h2: run-length partial sums (+fused relu) =================
__global__ __launch_bounds__(256) void pool_kernel(
    const ushort* __restrict__ h, const int* __restrict__ batch,
    float* __restrict__ gsum, float* __restrict__ cnt, int n)
{
    int wave = threadIdx.x >> 6, lane = threadIdx.x & 63;
    int start = blockIdx.x * 256 + wave * 64;
    int end = min(start + 64, n);
    if (start >= end) return;
    int cur = batch[start];
    float a0 = 0.f, a1 = 0.f;
    int run = 0;
    for (int node = start; node < end; ++node) {
        int g = batch[node];
        if (g != cur) {
            atomicAdd(&gsum[cur * HH + 2 * lane], a0);
            atomicAdd(&gsum[cur * HH + 2 * lane + 1], a1);
            if (lane == 0) atomicAdd(&cnt[cur], (float)run);
            cur = g; a0 = a1 = 0.f; run = 0;
        }
        uint x = ((const uint*)h)[(size_t)node * 64 + lane];
        a0 += fmaxf(b2f((ushort)x), 0.f);
        a1 += fmaxf(b2f((ushort)(x >> 16)), 0.f);
        ++run;
    }
    atomicAdd(&gsum[cur * HH + 2 * lane], a0);
    atomicAdd(&gsum[cur * HH + 2 * lane + 1], a1);
    if (lane == 0) atomicAdd(&cnt[cur], (float)run);
}

__global__ void pool_fin_kernel(const float* __restrict__ gsum,
                                const float* __restrict__ cnt, float* __restrict__ g)
{
    int i = blockIdx.x * blockDim.x + threadIdx.x;
    if (i < BB * HH) g[i] = gsum[i] / fmaxf(cnt[i / HH], 1.0f);
}

// ================= output heads =================
__global__ void out_heads_kernel(
    const float* __restrict__ g,
    const float* __restrict__ w0, const float* __restrict__ b0,
    const float* __restrict__ w1, const float* __restrict__ b1,
    const float* __restrict__ w2, const float* __restrict__ b2,
    const float* __restrict__ w3, const float* __restrict__ b3,
    const float* __restrict__ w4, const float* __restrict__ b4,
    const float* __restrict__ w5, const float* __restrict__ b5,
    const float* __restrict__ w6, const float* __restrict__ b6,
    float* __restrict__ out, int total)
{
    int t = blockIdx.x * blockDim.x + threadIdx.x;
    if (t >= total) return;
    const float* W; const float* bias; int cols; int local;
    if      (t < 64)    { W = w0; bias = b0; cols = 1;   local = t; }
    else if (t < 320)   { W = w1; bias = b1; cols = 4;   local = t - 64; }
    else if (t < 512)   { W = w2; bias = b2; cols = 3;   local = t - 320; }
    else if (t < 33280) { W = w3; bias = b3; cols = SS;  local = t - 512; }
    else if (t < 66048) { W = w4; bias = b4; cols = SS;  local = t - 33280; }
    else if (t < 98816) { W = w5; bias = b5; cols = SS;  local = t - 66048; }
    else                { W = w6; bias = b6; cols = LCC; local = t - 98816; }
    int b = local / cols, c = local % cols;
    const float* gr = g + b * HH;
    float acc = bias[c];
#pragma unroll 8
    for (int i = 0; i < HH; ++i) acc += gr[i] * W[i * cols + c];
    out[t] = acc;
}

// ================= orchestration =================
extern "C" void kernel_launch(void* const* d_in, const int* in_sizes, int n_in,
                              void* d_out, int out_size, void* d_ws, size_t ws_size,
                              hipStream_t stream)
{
    (void)in_sizes; (void)n_in; (void)out_size; (void)ws_size;

    const float* nf   = (const float*)d_in[0];
    const int*   ei   = (const int*)d_in[1];
    const int*   src  = ei;
    const int*   dst  = ei + EE;
    const int*   batch= (const int*)d_in[2];
    const float* Wp   = (const float*)d_in[3];
    const float* bp   = (const float*)d_in[4];
    const float* Wq1  = (const float*)d_in[5];
    const float* bq1  = (const float*)d_in[6];
    const float* Wk1  = (const float*)d_in[7];
    const float* bk1  = (const float*)d_in[8];
    const float* Wv1  = (const float*)d_in[9];
    const float* bv1  = (const float*)d_in[10];
    const float* Ws1  = (const float*)d_in[11];
    const float* bs1  = (const float*)d_in[12];
    const float* Wq2  = (const float*)d_in[13];
    const float* bq2  = (const float*)d_in[14];
    const float* Wk2  = (const float*)d_in[15];
    const float* bk2  = (const float*)d_in[16];
    const float* Wv2  = (const float*)d_in[17];
    const float* bv2  = (const float*)d_in[18];
    const float* Ws2  = (const float*)d_in[19];
    const float* bs2  = (const float*)d_in[20];
    const float* crW  = (const float*)d_in[21];
    const float* crb  = (const float*)d_in[22];
    const float* hlW  = (const float*)d_in[23];
    const float* hlb  = (const float*)d_in[24];
    const float* mtW  = (const float*)d_in[25];
    const float* mtb  = (const float*)d_in[26];
    const float* p1W  = (const float*)d_in[27];
    const float* p1b  = (const float*)d_in[28];
    const float* p2W  = (const float*)d_in[29];
    const float* p2b  = (const float*)d_in[30];
    const float* dtW  = (const float*)d_in[31];
    const float* dtb  = (const float*)d_in[32];
    const float* slW  = (const float*)d_in[33];
    const float* slb  = (const float*)d_in[34];
    float* out = (float*)d_out;

    (void)bk1;   // bk1 contributes only a per-dst-constant score shift (cancels in softmax)

    // ---- workspace layout (~167 MB; r14/r16-proven) ----
    ushort* Qbase  = (ushort*)d_ws;                        // N*1024 (4 x [u|v] head buffers)
    ushort* nfb    = Qbase;
    ushort* h2sb   = Qbase;                                // N*128
    ushort* qkvO   = Qbase + (size_t)NN * 256;             // N*384
    ushort* h2     = Qbase + (size_t)NN * 640;             // N*128
    ushort* h0b    = Qbase + (size_t)NN * 1024;            // N*128
    ushort* h1b    = h0b + (size_t)NN * 128;               // N*512 (conv1 skip AND out, in-place)
    ushort* wt     = h1b + (size_t)NN * 512;               // prepped weights
    float*  bb     = (float*)(wt + WTOTAL);                // fused biases
    int*    rowptr = (int*)(bb + BTOT);                    // N+1
    int*    srcs   = rowptr + NN + 1;                      // E
    int*    cnt    = srcs + EE;                            // N   (zeroed together with gsum/cntb)
    float*  gsum   = (float*)(cnt + NN);                   // B*128
    float*  cntb   = gsum + BB * HH;                       // B
    int*    cursor = (int*)(cntb + BB);                    // N
    int*    bsum   = cursor + NN;                          // 64
    float*  gbuf   = (float*)(bsum + 64);                  // B*128

    const float scale = 0.08838834764831845f; // 1/sqrt(128)
    const dim3 blk(256);
    const int gy  = (NN + BM - 1) / BM;         // 391 row-blocks
    const int gyp = ((gy + 7) / 8) * 8;         // 392 (XCD-padded)
    const int nb = (NN + SCAN_B - 1) / SCAN_B;  // 49

    // 1) weight prep + bilinear M/r composition
    wprep_kernel<<<(WTOTAL + BTOT + 255) / 256, blk, 0, stream>>>(
        Wp, Wq1, Wk1, Wv1, Ws1, Wq2, Wk2, Wv2, Ws2,
        bs1, bv1, bs2, bq2, bk2, bv2, wt, bb);
    mcomp_kernel<<<(HEADS * 128 * 128 + HEADS * 128 + 255) / 256, blk, 0, stream>>>(
        Wq1, Wk1, bq1, wt, bb);

    // 2) nf -> bf16
    f32_to_bf16_kernel<<<((NN * FF / 4) + 255) / 256, blk, 0, stream>>>(
        (const float4*)nf, (uint2*)nfb, NN * FF / 4);

    // 3) CSR build (r14-proven parallel 3-dispatch scan)
    fill_kernel<<<(NN + BB * HH + BB + 255) / 256, blk, 0, stream>>>(
        (unsigned*)cnt, 0u, NN + BB * HH + BB);
    hist_kernel<<<(EE + 255) / 256, blk, 0, stream>>>(dst, cnt, EE);
    scan_bsum_kernel<<<nb, blk, 0, stream>>>(cnt, bsum, NN);
    scan_excl_kernel<<<1, 64, 0, stream>>>(bsum, nb);
    scan_final_kernel<<<nb, blk, 0, stream>>>(cnt, bsum, rowptr, cursor, NN);
    bucket_kernel<<<(EE + 255) / 256, blk, 0, stream>>>(src, dst, cursor, srcs, EE);

    // 4) proj: h0b = relu(nf @ Wp + bp)   (mode 0, gx=1, K=64)
    gemm_bf16<<<dim3(1 * gyp), blk, 0, stream>>>(
        nfb, wt, bp, h0b, HH, h0b, 0, NN, FF, 1, 1, gy);

    // 5) F1-mega: [skip(512)->h1b | per head u|v -> Qbase+h*N*256]   (mode 1, gx=12, K=128)
    gemm_bf16<<<dim3(12 * gyp), blk, 0, stream>>>(
        h0b, wt + F1OFF, bb, h1b, 512, Qbase, 1, NN, HH, 0, 12, gy);

    // 6) fused 4-head gather (one wave per node; k = h0, shared)
    gather4_kernel<<<(NN + 3) / 4, blk, 0, stream>>>(
        Qbase, h0b, rowptr, srcs, h1b, scale, NN);

    // 7) F2: [skip(128)->h2sb | qkv(384)->qkvO]   (mode 2, gx=4, K=512)
    gemm_bf16<<<dim3(4 * gyp), blk, 0, stream>>>(
        h1b, wt + F2OFF, bb + 1536, h2sb, 128, qkvO, 2, NN, 4 * HH, 0, 4, gy);

    // 8) gather conv2 (single head)
    edge_gather_kernel<<<(NN + 3) / 4, blk, 0, stream>>>(
        qkvO, rowptr, srcs, h2sb, h2, scale, NN);

    // 9) pool (relu fused, bf16 input) + finalize
    pool_kernel<<<(NN + 255) / 256, blk, 0, stream>>>(h2, batch, gsum, cntb, NN);
    pool_fin_kernel<<<(BB * HH + 255) / 256, blk, 0, stream>>>(gsum, cntb, gbuf);

    // 10) output heads
    const int total = BB * (1 + 4 + 3 + SS + SS + SS + LCC);
    out_heads_kernel<<<(total + 255) / 256, blk, 0, stream>>>(
        gbuf, crW, crb, hlW, hlb, mtW, mtb, p1W, p1b, p2W, p2b, dtW, dtb, slW, slb, out, total);
}

// Round 19
// 369.741 us; speedup vs baseline: 1.3005x; 1.0004x over previous
//
#include <hip/hip_runtime.h>
#include <hip/hip_bf16.h>

#define NN 50000
#define EE 100000
#define FF 64
#define HH 128
#define HEADS 4
#define BB 64
#define SS 512
#define LCC 8

// ---- bf16 helpers ----
__device__ __forceinline__ float b2f(ushort u) {
    return __uint_as_float(((unsigned)u) << 16);
}
__device__ __forceinline__ ushort f2b(float f) {
    unsigned u = __float_as_uint(f);
    unsigned r = (u + 0x7FFFu + ((u >> 16) & 1u)) >> 16;   // RNE
    return (ushort)r;
}
// packed RNE convert: 2 f32 -> 1 uint (low = a), maps to v_cvt_pk_bf16_f32
__device__ __forceinline__ uint f2b_pk(float a, float b) {
    __hip_bfloat162 h = __float22bfloat162_rn(make_float2(a, b));
    return *reinterpret_cast<uint*>(&h);
}

typedef __attribute__((ext_vector_type(4))) float f32x4;
typedef __attribute__((ext_vector_type(8))) short s16x8;
typedef __attribute__((ext_vector_type(4))) uint u32x4;

__device__ __forceinline__ void glls16(const ushort* g, ushort* l) {
    __builtin_amdgcn_global_load_lds((const __attribute__((address_space(1))) void*)g,
                                     (__attribute__((address_space(3))) void*)l, 16, 0, 0);
}

// ================= bf16 MFMA GEMM (r12-proven core + packed-cvt epilogue) =================
#define BM 128
#define BN 128
#define BK 64
#define EST 68   // epilogue staging stride (f32) — breaks power-of-2 bank aliasing

__global__ __launch_bounds__(256) void gemm_bf16(
    const ushort* __restrict__ A, const ushort* __restrict__ Bt,
    const float* __restrict__ bias,
    ushort* __restrict__ C1, int ld1,
    ushort* __restrict__ C2b, int mode,
    int M, int K, int relu, int gx, int gy)
{
    __shared__ __align__(16) ushort Sm[2 * BM * BK];   // 32 KB: As | Bs, reused by epilogue
    ushort* As = Sm;
    ushort* Bs = Sm + BM * BK;

    const int bid  = blockIdx.x;
    const int xcd  = bid & 7;
    const int slot = bid >> 3;
    const int bx   = slot % gx;
    const int by   = xcd + 8 * (slot / gx);
    if (by >= gy) return;
    const int m0 = by * BM;
    const int n0 = bx * BN;

    const int t = threadIdx.x;
    const int lane = t & 63;
    const int wave = t >> 6;
    const int wm = (wave & 1) * 64;
    const int wn = (wave >> 1) * 64;
    const int lrow = lane & 15;
    const int g    = lane >> 4;

    const int srow = (wave << 5) + (lane >> 3);
    const int scs  = lane & 7;

    const ushort* ga[4];
    const ushort* gb[4];
#pragma unroll
    for (int p = 0; p < 4; ++p) {
        const int row = srow + (p << 3);
        const int l   = scs ^ (row & 7);
        ga[p] = A + (size_t)min(m0 + row, M - 1) * K + (l << 3);
        gb[p] = Bt + (size_t)(n0 + row) * K + (l << 3);
    }
    const int ldsoff = (wave << 11);

    f32x4 acc[4][4] = {};

    for (int k0 = 0; k0 < K; k0 += BK) {
#pragma unroll
        for (int p = 0; p < 4; ++p) glls16(ga[p] + k0, As + ldsoff + (p << 9));
#pragma unroll
        for (int p = 0; p < 4; ++p) glls16(gb[p] + k0, Bs + ldsoff + (p << 9));
        __syncthreads();

#pragma unroll
        for (int kk = 0; kk < 2; ++kk) {
            s16x8 af[4], bf[4];
#pragma unroll
            for (int i = 0; i < 4; ++i) {
                const int R = wm + i * 16 + lrow;
                const int c = ((kk << 2) + g) ^ (R & 7);
                af[i] = *(const s16x8*)&As[(R << 6) + (c << 3)];
            }
#pragma unroll
            for (int j = 0; j < 4; ++j) {
                const int R = wn + j * 16 + lrow;
                const int c = ((kk << 2) + g) ^ (R & 7);
                bf[j] = *(const s16x8*)&Bs[(R << 6) + (c << 3)];
            }
#pragma unroll
            for (int i = 0; i < 4; ++i)
#pragma unroll
                for (int j = 0; j < 4; ++j)
                    acc[i][j] = __builtin_amdgcn_mfma_f32_16x16x32_bf16(af[i], bf[j], acc[i][j], 0, 0, 0);
        }
        __syncthreads();
    }

    // ---- LDS-staged epilogue (packed cvt) ----
    float* Es = (float*)Sm + wave * (16 * EST);

    const int wbase = n0 + wn;
    ushort* Cw; int ldw, cb;
    if (mode == 0) { Cw = C1; ldw = ld1; cb = wbase; }
    else if (mode == 1) {
        if (wbase < 512) { Cw = C1; ldw = ld1; cb = wbase; }
        else {
            const int u = wbase - 512;
            const int h = u >> 8;                // 256 cols per head: u(128) | v(128)
            cb = u & 255;
            Cw = C2b + (size_t)h * NN * 256; ldw = 256;
        }
    } else {
        if (wbase < 128) { Cw = C1; ldw = 128; cb = wbase; }
        else             { Cw = C2b; ldw = 384; cb = wbase - 128; }
    }

    float bj[4];
#pragma unroll
    for (int j = 0; j < 4; ++j) bj[j] = bias[wbase + j * 16 + lrow];

    const int rbase = (lane >> 4) * 4;
    const int rrow  = lane >> 2;
    const int rcol  = (lane & 3) << 4;

#pragma unroll
    for (int i = 0; i < 4; ++i) {
#pragma unroll
        for (int j = 0; j < 4; ++j)
#pragma unroll
            for (int r = 0; r < 4; ++r) {
                float v = acc[i][j][r] + bj[j];
                if (relu) v = fmaxf(v, 0.f);
                Es[(rbase + r) * EST + j * 16 + lrow] = v;
            }
        const int gm = m0 + wm + i * 16 + rrow;
        if (gm < M) {
            const float* src = Es + rrow * EST + rcol;
            f32x4 f0 = *(const f32x4*)(src + 0);
            f32x4 f1 = *(const f32x4*)(src + 4);
            f32x4 f2 = *(const f32x4*)(src + 8);
            f32x4 f3 = *(const f32x4*)(src + 12);
            u32x4 o0, o1;
            o0[0] = f2b_pk(f0[0], f0[1]); o0[1] = f2b_pk(f0[2], f0[3]);
            o0[2] = f2b_pk(f1[0], f1[1]); o0[3] = f2b_pk(f1[2], f1[3]);
            o1[0] = f2b_pk(f2[0], f2[1]); o1[1] = f2b_pk(f2[2], f2[3]);
            o1[2] = f2b_pk(f3[0], f3[1]); o1[3] = f2b_pk(f3[2], f3[3]);
            ushort* dst = Cw + (size_t)gm * ldw + cb + rcol;
            *(u32x4*)(dst + 0) = o0;
            *(u32x4*)(dst + 8) = o1;
        }
    }
}

// ================= weight prep + mcomp fused (disjoint writes) =================
// wt layout (rows [n][k], bf16):
//  [0, 8192)            Wpt   [128][64]
//  [8192, 204800)       F1    [1536][128] = Ws1t(512) | per head: u(128, M) | v(128)
//  [204800, 466944)     F2    [512][512]  = Ws2t(128) | q2|k2|v2 (384)
// bb: [0,512) bs1; per head [512+h*256,+128) r_h, [+128,+256) bv1; [1536,2048) F2
#define F1OFF  8192
#define F2OFF  204800
#define WTOTAL 466944
#define BTOT   2048
#define MWORK  (HEADS * 128 * 128 + HEADS * 128)   // 66048

__global__ void prep_kernel(
    const float* __restrict__ Wp,
    const float* __restrict__ Wq1, const float* __restrict__ Wk1,
    const float* __restrict__ Wv1, const float* __restrict__ Ws1,
    const float* __restrict__ Wq2, const float* __restrict__ Wk2,
    const float* __restrict__ Wv2, const float* __restrict__ Ws2,
    const float* __restrict__ bs1, const float* __restrict__ bq1,
    const float* __restrict__ bv1, const float* __restrict__ bs2,
    const float* __restrict__ bq2, const float* __restrict__ bk2, const float* __restrict__ bv2,
    ushort* __restrict__ wt, float* __restrict__ bb)
{
    int t = blockIdx.x * 256 + threadIdx.x;
    if (t < WTOTAL) {
        float v;
        if (t < F1OFF) {
            int n = t >> 6, k = t & 63;
            v = Wp[k * 128 + n];
        } else if (t < F2OFF) {
            int u = t - F1OFF;
            int n = u >> 7, k = u & 127;
            if (n < 512) v = Ws1[k * 512 + n];
            else {
                int r = n - 512;
                int h = r >> 8, c = r & 255;
                if (c < 128) return;             // u (M) rows: filled by mcomp branch
                v = Wv1[k * 512 + h * 128 + (c - 128)];
            }
        } else {
            int u = t - F2OFF;
            int n = u >> 9, k = u & 511;
            if (n < 128) v = Ws2[k * 128 + n];
            else {
                int r = n - 128;
                const float* W = (r < 128) ? Wq2 : (r < 256) ? Wk2 : Wv2;
                v = W[k * 128 + (r & 127)];
            }
        }
        wt[t] = f2b(v);
    } else if (t < WTOTAL + BTOT) {
        int u = t - WTOTAL;
        float v;
        if (u < 512) v = bs1[u];
        else if (u < 1536) {
            int r = u - 512;
            int h = r >> 8, c = r & 255;
            if (c < 128) return;                 // r_h bias: filled by mcomp branch
            v = bv1[h * 128 + (c - 128)];
        } else {
            int c = u - 1536;
            v = (c < 128) ? bs2[c]
              : (c < 256) ? bq2[c - 128]
              : (c < 384) ? bk2[c - 256] : bv2[c - 384];
        }
        bb[u] = v;
    } else if (t < WTOTAL + BTOT + MWORK) {
        int m = t - (WTOTAL + BTOT);
        if (m < HEADS * 128 * 128) {             // M_h[a][b] = Wq_h[:,a] . Wk_h[:,b]
            int h = m >> 14;
            int rem = m & 16383;
            int b = rem >> 7, a = rem & 127;
            const float* wq = Wq1 + a * 512 + h * 128;
            const float* wk = Wk1 + b * 512 + h * 128;
            float acc = 0.f;
#pragma unroll 8
            for (int d = 0; d < 128; ++d) acc += wq[d] * wk[d];
            wt[F1OFF + (size_t)(512 + h * 256 + b) * 128 + a] = f2b(acc);
        } else {                                 // r_h[b] = Wk_h[:,b] . bq_h
            int u = m - HEADS * 128 * 128;
            int h = u >> 7, b = u & 127;
            const float* wk = Wk1 + b * 512 + h * 128;
            const float* bq = bq1 + h * 128;
            float acc = 0.f;
#pragma unroll 8
            for (int d = 0; d < 128; ++d) acc += wk[d] * bq[d];
            bb[512 + h * 256 + b] = acc;
        }
    }
}

// ================= fp32 -> bf16 (x4, packed cvt) =================
__global__ void f32_to_bf16_kernel(const float4* __restrict__ in, uint2* __restrict__ out, int n4)
{
    int i = blockIdx.x * 256 + threadIdx.x;
    if (i >= n4) return;
    float4 v = in[i];
    uint2 o;
    o.x = f2b_pk(v.x, v.y);
    o.y = f2b_pk(v.z, v.w);
    out[i] = o;
}

__global__ void fill_kernel(unsigned* __restrict__ p, unsigned v, int n) {
    int i = blockIdx.x * blockDim.x + threadIdx.x;
    if (i < n) p[i] = v;
}

// ================= CSR build (dst -> src list) =================
__global__ void hist_kernel(const int* __restrict__ dst, int* __restrict__ cnt, int E) {
    int e = blockIdx.x * 256 + threadIdx.x;
    if (e < E) atomicAdd(&cnt[dst[e]], 1);
}

#define SCAN_B 1024
__global__ void scan_bsum_kernel(const int* __restrict__ cnt, int* __restrict__ bsum, int n) {
    __shared__ int sd[256];
    int tid = threadIdx.x;
    int base = blockIdx.x * SCAN_B + tid * 4;
    int s = 0;
#pragma unroll
    for (int j = 0; j < 4; ++j) if (base + j < n) s += cnt[base + j];
    sd[tid] = s;
    __syncthreads();
    for (int off = 128; off > 0; off >>= 1) {
        if (tid < off) sd[tid] += sd[tid + off];
        __syncthreads();
    }
    if (tid == 0) bsum[blockIdx.x] = sd[0];
}

// scan_final with fused exclusive block-prefix (reads RAW bsum; no scan_excl pass)
__global__ void scan_final_kernel(const int* __restrict__ cnt, const int* __restrict__ bsum,
                                  int* __restrict__ rowptr, int* __restrict__ cursor, int n) {
    __shared__ int sd[256];
    __shared__ int sb[256];
    int tid = threadIdx.x;
    // block base = sum of bsum[0..blockIdx.x)
    sb[tid] = (tid < blockIdx.x) ? bsum[tid] : 0;
    __syncthreads();
    for (int off = 128; off > 0; off >>= 1) {
        if (tid < off) sb[tid] += sb[tid + off];
        __syncthreads();
    }
    const int bbase = sb[0];

    int base = blockIdx.x * SCAN_B + tid * 4;
    int v[4]; int s = 0;
#pragma unroll
    for (int j = 0; j < 4; ++j) { v[j] = (base + j < n) ? cnt[base + j] : 0; s += v[j]; }
    sd[tid] = s;
    __syncthreads();
    for (int off = 1; off < 256; off <<= 1) {
        int t2 = (tid >= off) ? sd[tid - off] : 0;
        __syncthreads();
        sd[tid] += t2;
        __syncthreads();
    }
    int acc = bbase + sd[tid] - s;
#pragma unroll
    for (int j = 0; j < 4; ++j) {
        if (base + j < n) cursor[base + j] = acc;
        acc += v[j];
        if (base + j < n) rowptr[base + j + 1] = acc;
    }
    if (blockIdx.x == 0 && tid == 0) rowptr[0] = 0;
}

__global__ void bucket_kernel(const int* __restrict__ src, const int* __restrict__ dst,
                              int* __restrict__ cursor, int* __restrict__ srcs, int E) {
    int e = blockIdx.x * 256 + threadIdx.x;
    if (e >= E) return;
    int p = atomicAdd(&cursor[dst[e]], 1);
    srcs[p] = src[e];
}

// ================= conv1 gather: ALL 4 HEADS per wave, ILP-2 over edges =================
// Qb: 4 head buffers (stride NN*256 us), row = [u(128)|v(128)]. Kb = h0 rows (128 bf16).
// io: h1b rows (512 bf16) — skip in, result out, in place. relu fused.
// Per 2-edge chunk: 10 loads in flight (2 k + 8 v), then 8 interleaved butterflies.
__global__ __launch_bounds__(256) void gather4_kernel(
    const ushort* __restrict__ Qb, const ushort* __restrict__ Kb,
    const int* __restrict__ rowptr, const int* __restrict__ srcs,
    ushort* __restrict__ io, float scale, int n)
{
    int i = blockIdx.x * 4 + (threadIdx.x >> 6);
    int lane = threadIdx.x & 63;
    if (i >= n) return;
    const uint* Qu = (const uint*)Qb;        // row stride 128 uints per head-buffer
    const uint* Ku = (const uint*)Kb;        // row stride 64 uints

    float q0[4], q1[4];
#pragma unroll
    for (int h = 0; h < 4; ++h) {
        uint qv = Qu[((size_t)h * NN + i) * 128 + lane];
        q0[h] = b2f((ushort)qv); q1[h] = b2f((ushort)(qv >> 16));
    }
    int p0 = rowptr[i], p1 = rowptr[i + 1];
    float den[4] = {0.f, 0.f, 0.f, 0.f};
    float o0[4] = {0.f, 0.f, 0.f, 0.f};
    float o1[4] = {0.f, 0.f, 0.f, 0.f};
    int p = p0;
    for (; p + 2 <= p1; p += 2) {                 // two edges in flight
        int s0 = srcs[p], s1 = srcs[p + 1];
        uint kva = Ku[(size_t)s0 * 64 + lane];
        uint kvb = Ku[(size_t)s1 * 64 + lane];
        uint vva[4], vvb[4];
#pragma unroll
        for (int h = 0; h < 4; ++h) vva[h] = Qu[((size_t)h * NN + s0) * 128 + 64 + lane];
#pragma unroll
        for (int h = 0; h < 4; ++h) vvb[h] = Qu[((size_t)h * NN + s1) * 128 + 64 + lane];
        float ka0 = b2f((ushort)kva), ka1 = b2f((ushort)(kva >> 16));
        float kb0 = b2f((ushort)kvb), kb1 = b2f((ushort)(kvb >> 16));
        float da[4], db[4];
#pragma unroll
        for (int h = 0; h < 4; ++h) {
            da[h] = q0[h] * ka0 + q1[h] * ka1;
            db[h] = q0[h] * kb0 + q1[h] * kb1;
        }
#pragma unroll
        for (int off = 32; off > 0; off >>= 1) {
#pragma unroll
            for (int h = 0; h < 4; ++h) {
                da[h] += __shfl_xor(da[h], off, 64);
                db[h] += __shfl_xor(db[h], off, 64);
            }
        }
#pragma unroll
        for (int h = 0; h < 4; ++h) {
            float ea = __expf(da[h] * scale);
            float eb = __expf(db[h] * scale);
            den[h] += ea + eb;
            o0[h] += ea * b2f((ushort)vva[h]) + eb * b2f((ushort)vvb[h]);
            o1[h] += ea * b2f((ushort)(vva[h] >> 16)) + eb * b2f((ushort)(vvb[h] >> 16));
        }
    }
    if (p < p1) {                                 // tail edge
        int s = srcs[p];
        uint kv = Ku[(size_t)s * 64 + lane];
        uint vv[4];
#pragma unroll
        for (int h = 0; h < 4; ++h) vv[h] = Qu[((size_t)h * NN + s) * 128 + 64 + lane];
        float k0 = b2f((ushort)kv), k1 = b2f((ushort)(kv >> 16));
        float d[4];
#pragma unroll
        for (int h = 0; h < 4; ++h) d[h] = q0[h] * k0 + q1[h] * k1;
#pragma unroll
        for (int off = 32; off > 0; off >>= 1) {
#pragma unroll
            for (int h = 0; h < 4; ++h) d[h] += __shfl_xor(d[h], off, 64);
        }
#pragma unroll
        for (int h = 0; h < 4; ++h) {
            float e = __expf(d[h] * scale);
            den[h] += e;
            o0[h] += e * b2f((ushort)vv[h]);
            o1[h] += e * b2f((ushort)(vv[h] >> 16));
        }
    }
#pragma unroll
    for (int h = 0; h < 4; ++h) {
        uint sk = ((const uint*)io)[(size_t)i * 256 + h * 64 + lane];
        float inv = 1.0f / (den[h] + 1e-16f);
        float r0 = fmaxf(b2f((ushort)sk) + o0[h] * inv, 0.f);
        float r1 = fmaxf(b2f((ushort)(sk >> 16)) + o1[h] * inv, 0.f);
        ((uint*)io)[(size_t)i * 256 + h * 64 + lane] = f2b_pk(r0, r1);
    }
}

// ================= conv2 gather (single head, q|k|v rows ld=384, ILP-2) =================
__global__ __launch_bounds__(256) void edge_gather_kernel(
    const ushort* __restrict__ qkv,
    const int* __restrict__ rowptr, const int* __restrict__ srcs,
    const ushort* __restrict__ skip,
    ushort* __restrict__ outp, float scale, int n)
{
    int i = blockIdx.x * 4 + (threadIdx.x >> 6);
    int lane = threadIdx.x & 63;
    if (i >= n) return;
    const uint* Qu = (const uint*)qkv;       // row stride 192 uints

    uint sk = ((const uint*)skip)[(size_t)i * 64 + lane];
    uint qv = Qu[(size_t)i * 192 + lane];
    float q0 = b2f((ushort)qv), q1 = b2f((ushort)(qv >> 16));
    int p0 = rowptr[i], p1 = rowptr[i + 1];
    float den = 0.f, o0 = 0.f, o1 = 0.f;
    int p = p0;
    for (; p + 2 <= p1; p += 2) {
        int s0 = srcs[p], s1 = srcs[p + 1];
        const uint* kr0 = Qu + (size_t)s0 * 192 + 64;
        const uint* kr1 = Qu + (size_t)s1 * 192 + 64;
        uint kv0 = kr0[lane], vv0 = kr0[lane + 64];
        uint kv1 = kr1[lane], vv1 = kr1[lane + 64];
        float d0 = q0 * b2f((ushort)kv0) + q1 * b2f((ushort)(kv0 >> 16));
        float d1 = q0 * b2f((ushort)kv1) + q1 * b2f((ushort)(kv1 >> 16));
#pragma unroll
        for (int off = 32; off > 0; off >>= 1) {
            d0 += __shfl_xor(d0, off, 64);
            d1 += __shfl_xor(d1, off, 64);
        }
        float e0 = __expf(d0 * scale), e1 = __expf(d1 * scale);
        den += e0 + e1;
        o0 += e0 * b2f((ushort)vv0) + e1 * b2f((ushort)vv1);
        o1 += e0 * b2f((ushort)(vv0 >> 16)) + e1 * b2f((ushort)(vv1 >> 16));
    }
    if (p < p1) {
        int s = srcs[p];
        const uint* kr = Qu + (size_t)s * 192 + 64;
        uint kv = kr[lane], vv = kr[lane + 64];
        float d = q0 * b2f((ushort)kv) + q1 * b2f((ushort)(kv >> 16));
#pragma unroll
        for (int off = 32; off > 0; off >>= 1) d += __shfl_xor(d, off, 64);
        float e = __expf(d * scale);
        den += e;
        o0 += e * b2f((ushort)vv);
        o1 += e * b2f((ushort)(vv >> 16));
    }
    float inv = 1.0f / (den + 1e-16f);
    float r0 = b2f((ushort)sk) + o0 * inv;
    float r1 = b2f((ushort)(sk >> 16)) + o1 * inv;
    ((uint*)outp)[(size_t)i * 64 + lane] = f2b_pk(r0, r1);
}

// ================= pool over bf16 h2: run-length partial sums (+fused relu) =================
__global__ __launch_bounds__(256) void pool_kernel(
    const ushort* __restrict__ h, const int* __restrict__ batch,
    float* __restrict__ gsum, float* __restrict__ cnt, int n)
{
    int wave = threadIdx.x >> 6, lane = threadIdx.x & 63;
    int start = blockIdx.x * 256 + wave * 64;
    int end = min(start + 64, n);
    if (start >= end) return;
    int cur = batch[start];
    float a0 = 0.f, a1 = 0.f;
    int run = 0;
    for (int node = start; node < end; ++node) {
        int g = batch[node];
        if (g != cur) {
            atomicAdd(&gsum[cur * HH + 2 * lane], a0);
            atomicAdd(&gsum[cur * HH + 2 * lane + 1], a1);
            if (lane == 0) atomicAdd(&cnt[cur], (float)run);
            cur = g; a0 = a1 = 0.f; run = 0;
        }
        uint x = ((const uint*)h)[(size_t)node * 64 + lane];
        a0 += fmaxf(b2f((ushort)x), 0.f);
        a1 += fmaxf(b2f((ushort)(x >> 16)), 0.f);
        ++run;
    }
    atomicAdd(&gsum[cur * HH + 2 * lane], a0);
    atomicAdd(&gsum[cur * HH + 2 * lane + 1], a1);
    if (lane == 0) atomicAdd(&cnt[cur], (float)run);
}

__global__ void pool_fin_kernel(const float* __restrict__ gsum,
                                const float* __restrict__ cnt, float* __restrict__ g)
{
    int i = blockIdx.x * blockDim.x + threadIdx.x;
    if (i < BB * HH) g[i] = gsum[i] / fmaxf(cnt[i / HH], 1.0f);
}

// ================= output heads =================
__global__ void out_heads_kernel(
    const float* __restrict__ g,
    const float* __restrict__ w0, const float* __restrict__ b0,
    const float* __restrict__ w1, const float* __restrict__ b1,
    const float* __restrict__ w2, const float* __restrict__ b2,
    const float* __restrict__ w3, const float* __restrict__ b3,
    const float* __restrict__ w4, const float* __restrict__ b4,
    const float* __restrict__ w5, const float* __restrict__ b5,
    const float* __restrict__ w6, const float* __restrict__ b6,
    float* __restrict__ out, int total)
{
    int t = blockIdx.x * blockDim.x + threadIdx.x;
    if (t >= total) return;
    const float* W; const float* bias; int cols; int local;
    if      (t < 64)    { W = w0; bias = b0; cols = 1;   local = t; }
    else if (t < 320)   { W = w1; bias = b1; cols = 4;   local = t - 64; }
    else if (t < 512)   { W = w2; bias = b2; cols = 3;   local = t - 320; }
    else if (t < 33280) { W = w3; bias = b3; cols = SS;  local = t - 512; }
    else if (t < 66048) { W = w4; bias = b4; cols = SS;  local = t - 33280; }
    else if (t < 98816) { W = w5; bias = b5; cols = SS;  local = t - 66048; }
    else                { W = w6; bias = b6; cols = LCC; local = t - 98816; }
    int b = local / cols, c = local % cols;
    const float* gr = g + b * HH;
    float acc = bias[c];
#pragma unroll 8
    for (int i = 0; i < HH; ++i) acc += gr[i] * W[i * cols + c];
    out[t] = acc;
}

// ================= orchestration =================
extern "C" void kernel_launch(void* const* d_in, const int* in_sizes, int n_in,
                              void* d_out, int out_size, void* d_ws, size_t ws_size,
                              hipStream_t stream)
{
    (void)in_sizes; (void)n_in; (void)out_size; (void)ws_size;

    const float* nf   = (const float*)d_in[0];
    const int*   ei   = (const int*)d_in[1];
    const int*   src  = ei;
    const int*   dst  = ei + EE;
    const int*   batch= (const int*)d_in[2];
    const float* Wp   = (const float*)d_in[3];
    const float* bp   = (const float*)d_in[4];
    const float* Wq1  = (const float*)d_in[5];
    const float* bq1  = (const float*)d_in[6];
    const float* Wk1  = (const float*)d_in[7];
    const float* bk1  = (const float*)d_in[8];
    const float* Wv1  = (const float*)d_in[9];
    const float* bv1  = (const float*)d_in[10];
    const float* Ws1  = (const float*)d_in[11];
    const float* bs1  = (const float*)d_in[12];
    const float* Wq2  = (const float*)d_in[13];
    const float* bq2  = (const float*)d_in[14];
    const float* Wk2  = (const float*)d_in[15];
    const float* bk2  = (const float*)d_in[16];
    const float* Wv2  = (const float*)d_in[17];
    const float* bv2  = (const float*)d_in[18];
    const float* Ws2  = (const float*)d_in[19];
    const float* bs2  = (const float*)d_in[20];
    const float* crW  = (const float*)d_in[21];
    const float* crb  = (const float*)d_in[22];
    const float* hlW  = (const float*)d_in[23];
    const float* hlb  = (const float*)d_in[24];
    const float* mtW  = (const float*)d_in[25];
    const float* mtb  = (const float*)d_in[26];
    const float* p1W  = (const float*)d_in[27];
    const float* p1b  = (const float*)d_in[28];
    const float* p2W  = (const float*)d_in[29];
    const float* p2b  = (const float*)d_in[30];
    const float* dtW  = (const float*)d_in[31];
    const float* dtb  = (const float*)d_in[32];
    const float* slW  = (const float*)d_in[33];
    const float* slb  = (const float*)d_in[34];
    float* out = (float*)d_out;

    (void)bk1;   // bk1 contributes only a per-dst-constant score shift (cancels in softmax)

    // ---- workspace layout (~167 MB; r14/r16-proven) ----
    ushort* Qbase  = (ushort*)d_ws;                        // N*1024 (4 x [u|v] head buffers)
    ushort* nfb    = Qbase;
    ushort* h2sb   = Qbase;                                // N*128
    ushort* qkvO   = Qbase + (size_t)NN * 256;             // N*384
    ushort* h2     = Qbase + (size_t)NN * 640;             // N*128
    ushort* h0b    = Qbase + (size_t)NN * 1024;            // N*128
    ushort* h1b    = h0b + (size_t)NN * 128;               // N*512 (conv1 skip AND out, in-place)
    ushort* wt     = h1b + (size_t)NN * 512;               // prepped weights
    float*  bb     = (float*)(wt + WTOTAL);                // fused biases
    int*    rowptr = (int*)(bb + BTOT);                    // N+1
    int*    srcs   = rowptr + NN + 1;                      // E
    int*    cnt    = srcs + EE;                            // N   (zeroed together with gsum/cntb)
    float*  gsum   = (float*)(cnt + NN);                   // B*128
    float*  cntb   = gsum + BB * HH;                       // B
    int*    cursor = (int*)(cntb + BB);                    // N
    int*    bsum   = cursor + NN;                          // 64
    float*  gbuf   = (float*)(bsum + 64);                  // B*128

    const float scale = 0.08838834764831845f; // 1/sqrt(128)
    const dim3 blk(256);
    const int gy  = (NN + BM - 1) / BM;         // 391 row-blocks
    const int gyp = ((gy + 7) / 8) * 8;         // 392 (XCD-padded)
    const int nb = (NN + SCAN_B - 1) / SCAN_B;  // 49

    // 1) weight prep + bilinear M/r composition (fused)
    prep_kernel<<<(WTOTAL + BTOT + MWORK + 255) / 256, blk, 0, stream>>>(
        Wp, Wq1, Wk1, Wv1, Ws1, Wq2, Wk2, Wv2, Ws2,
        bs1, bq1, bv1, bs2, bq2, bk2, bv2, wt, bb);

    // 2) nf -> bf16
    f32_to_bf16_kernel<<<((NN * FF / 4) + 255) / 256, blk, 0, stream>>>(
        (const float4*)nf, (uint2*)nfb, NN * FF / 4);

    // 3) CSR build (scan_excl fused into scan_final)
    fill_kernel<<<(NN + BB * HH + BB + 255) / 256, blk, 0, stream>>>(
        (unsigned*)cnt, 0u, NN + BB * HH + BB);
    hist_kernel<<<(EE + 255) / 256, blk, 0, stream>>>(dst, cnt, EE);
    scan_bsum_kernel<<<nb, blk, 0, stream>>>(cnt, bsum, NN);
    scan_final_kernel<<<nb, blk, 0, stream>>>(cnt, bsum, rowptr, cursor, NN);
    bucket_kernel<<<(EE + 255) / 256, blk, 0, stream>>>(src, dst, cursor, srcs, EE);

    // 4) proj: h0b = relu(nf @ Wp + bp)   (mode 0, gx=1, K=64)
    gemm_bf16<<<dim3(1 * gyp), blk, 0, stream>>>(
        nfb, wt, bp, h0b, HH, h0b, 0, NN, FF, 1, 1, gy);

    // 5) F1-mega: [skip(512)->h1b | per head u|v -> Qbase+h*N*256]   (mode 1, gx=12, K=128)
    gemm_bf16<<<dim3(12 * gyp), blk, 0, stream>>>(
        h0b, wt + F1OFF, bb, h1b, 512, Qbase, 1, NN, HH, 0, 12, gy);

    // 6) fused 4-head gather, ILP-2 over edges (one wave per node; k = h0, shared)
    gather4_kernel<<<(NN + 3) / 4, blk, 0, stream>>>(
        Qbase, h0b, rowptr, srcs, h1b, scale, NN);

    // 7) F2: [skip(128)->h2sb | qkv(384)->qkvO]   (mode 2, gx=4, K=512)
    gemm_bf16<<<dim3(4 * gyp), blk, 0, stream>>>(
        h1b, wt + F2OFF, bb + 1536, h2sb, 128, qkvO, 2, NN, 4 * HH, 0, 4, gy);

    // 8) gather conv2 (single head)
    edge_gather_kernel<<<(NN + 3) / 4, blk, 0, stream>>>(
        qkvO, rowptr, srcs, h2sb, h2, scale, NN);

    // 9) pool (relu fused, bf16 input) + finalize
    pool_kernel<<<(NN + 255) / 256, blk, 0, stream>>>(h2, batch, gsum, cntb, NN);
    pool_fin_kernel<<<(BB * HH + 255) / 256, blk, 0, stream>>>(gsum, cntb, gbuf);

    // 10) output heads
    const int total = BB * (1 + 4 + 3 + SS + SS + SS + LCC);
    out_heads_kernel<<<(total + 255) / 256, blk, 0, stream>>>(
        gbuf, crW, crb, hlW, hlb, mtW, mtb, p1W, p1b, p2W, p2b, dtW, dtb, slW, slb, out, total);
}